// Round 1
// baseline (1261.639 us; speedup 1.0000x reference)
//
#include <hip/hip_runtime.h>

#define B_    4
#define C_    256
#define H_    64
#define W_    64
#define HW_   4096
#define NG_   32
#define CPG_  8
#define KK_   9
#define NOFF_ 18

// ---------------------------------------------------------------------------
// K1: GroupNorm (32 groups) + ReLU. One block per (b, group); group = 8
// contiguous channels = 32768 contiguous floats.
// ---------------------------------------------------------------------------
__global__ __launch_bounds__(256) void gn_relu_kernel(
    const float* __restrict__ in, const float* __restrict__ gamma,
    const float* __restrict__ beta, float* __restrict__ out)
{
    int b = blockIdx.x >> 5;
    int g = blockIdx.x & 31;
    const int N = CPG_ * HW_;              // 32768
    size_t base = ((size_t)(b * C_ + g * CPG_)) * HW_;
    const float4* in4 = (const float4*)(in + base);
    int t = threadIdx.x;

    float s = 0.f, ss = 0.f;
    for (int i = t; i < N / 4; i += 256) {
        float4 v = in4[i];
        s  += v.x + v.y + v.z + v.w;
        ss += v.x * v.x + v.y * v.y + v.z * v.z + v.w * v.w;
    }
    #pragma unroll
    for (int off = 32; off > 0; off >>= 1) {
        s  += __shfl_down(s, off, 64);
        ss += __shfl_down(ss, off, 64);
    }
    __shared__ float red[16];
    __shared__ float sh_rs, sh_m;
    int wid = t >> 6;
    if ((t & 63) == 0) { red[wid] = s; red[8 + wid] = ss; }
    __syncthreads();
    if (t == 0) {
        float S  = red[0] + red[1] + red[2] + red[3];
        float SS = red[8] + red[9] + red[10] + red[11];
        float m = S / (float)N;
        float var = SS / (float)N - m * m;
        sh_rs = rsqrtf(var + 1e-5f);
        sh_m = m;
    }
    __syncthreads();
    float rs = sh_rs, m = sh_m;
    float4* out4 = (float4*)(out + base);
    for (int i = t; i < N / 4; i += 256) {
        int ch = g * CPG_ + (i >> 10);          // i*4/4096
        float ga = gamma[ch] * rs;
        float be = beta[ch] - m * ga;
        float4 v = in4[i];
        float4 o;
        o.x = fmaxf(fmaf(v.x, ga, be), 0.f);
        o.y = fmaxf(fmaf(v.y, ga, be), 0.f);
        o.z = fmaxf(fmaf(v.z, ga, be), 0.f);
        o.w = fmaxf(fmaf(v.w, ga, be), 0.f);
        out4[i] = o;
    }
}

// ---------------------------------------------------------------------------
// K2: depthwise 7x7 SAME conv (cross-correlation, zero pad 3).
// One block per (b,c) plane; plane + halo staged in LDS.
// ---------------------------------------------------------------------------
__global__ __launch_bounds__(256) void dw7_kernel(
    const float* __restrict__ in, const float* __restrict__ dwk,
    float* __restrict__ out)
{
    int plane = blockIdx.x;                // b*C + c
    int c = plane & (C_ - 1);
    const float* src = in + (size_t)plane * HW_;
    float* dst = out + (size_t)plane * HW_;
    __shared__ float tile[70 * 72];
    __shared__ float wk[49];
    int t = threadIdx.x;
    if (t < 49) wk[t] = dwk[c * 49 + t];
    for (int i = t; i < 70 * 72; i += 256) tile[i] = 0.f;
    __syncthreads();
    for (int i = t; i < HW_; i += 256) {
        int y = i >> 6, x = i & 63;
        tile[(y + 3) * 72 + (x + 3)] = src[i];
    }
    __syncthreads();
    for (int i = t; i < HW_; i += 256) {
        int y = i >> 6, x = i & 63;
        float acc = 0.f;
        #pragma unroll
        for (int dy = 0; dy < 7; ++dy)
            #pragma unroll
            for (int dx = 0; dx < 7; ++dx)
                acc = fmaf(tile[(y + dy) * 72 + x + dx], wk[dy * 7 + dx], acc);
        dst[i] = acc;
    }
}

// ---------------------------------------------------------------------------
// K3: pointwise 256->18 conv + bias (OFFSET_SCALE == 1.0 so no extra scale).
// One thread per pixel, 18 accumulators; pw weights staged in LDS.
// grid = B*HW/256 = 64 blocks.
// ---------------------------------------------------------------------------
__global__ __launch_bounds__(256) void pw_off_kernel(
    const float* __restrict__ f, const float* __restrict__ pw,
    const float* __restrict__ pwb, float* __restrict__ off)
{
    int b = blockIdx.x >> 4;
    int pbase = (blockIdx.x & 15) * 256;
    __shared__ float wl[NOFF_ * C_];
    int t = threadIdx.x;
    for (int i = t; i < NOFF_ * C_; i += 256) wl[i] = pw[i];
    __syncthreads();
    int p = pbase + t;
    const float* fb = f + (size_t)b * C_ * HW_ + p;
    float acc[NOFF_];
    #pragma unroll
    for (int o = 0; o < NOFF_; ++o) acc[o] = pwb[o];
    for (int c = 0; c < C_; ++c) {
        float v = fb[(size_t)c * HW_];
        #pragma unroll
        for (int o = 0; o < NOFF_; ++o)
            acc[o] = fmaf(wl[o * C_ + c], v, acc[o]);
    }
    float* ob = off + (size_t)b * NOFF_ * HW_ + p;
    #pragma unroll
    for (int o = 0; o < NOFF_; ++o) ob[(size_t)o * HW_] = acc[o];
}

// ---------------------------------------------------------------------------
// K4: weight transpose w[o][c][k] -> wt[c][k][o] (o contiguous for staging)
// ---------------------------------------------------------------------------
__global__ __launch_bounds__(256) void wt_kernel(
    const float* __restrict__ w, float* __restrict__ wt)
{
    int idx = blockIdx.x * 256 + threadIdx.x;   // 589824 total = 2304 blocks
    int k = idx % KK_;
    int c = (idx / KK_) & (C_ - 1);
    int o = idx / (KK_ * C_);
    wt[((size_t)c * KK_ + k) * C_ + o] = w[idx];
}

// ---------------------------------------------------------------------------
// K5: fused deformable gather + einsum ('bckhw,ock->bohw') + bias (+residual)
// One block per (b,row): 256 outputs x 64 pixels. Bilinear corner indices /
// weights precomputed once per (k,pixel) with OOB folded into zero weights
// (matches reference clip+valid semantics; bilinear is continuous so this is
// exact). Channel loop stages sampled[9][64] + wt[c][9][256] in LDS; each
// thread accumulates an 8(o) x 8(p) register tile.
// ---------------------------------------------------------------------------
__global__ __launch_bounds__(256) void deform_kernel(
    const float* __restrict__ h, const float* __restrict__ off,
    const float* __restrict__ wt, const float* __restrict__ bias,
    const float* __restrict__ resid, float* __restrict__ out)
{
    int b = blockIdx.x >> 6;
    int row = blockIdx.x & 63;
    __shared__ int   i00[576], i01[576], i10[576], i11[576];
    __shared__ float c00[576], c01[576], c10[576], c11[576];
    __shared__ __align__(16) float slds[KK_ * 64];
    __shared__ __align__(16) float wlds[KK_ * C_];
    int t = threadIdx.x;

    for (int e = t; e < 576; e += 256) {
        int k = e >> 6, p = e & 63;
        float offy = off[((size_t)(b * NOFF_) + 2 * k) * HW_ + row * 64 + p];
        float offx = off[((size_t)(b * NOFF_) + 2 * k + 1) * HW_ + row * 64 + p];
        float py = (float)row + (float)(k / 3 - 1) + offy;
        float px = (float)p   + (float)(k % 3 - 1) + offx;
        float y0f = floorf(py), x0f = floorf(px);
        float wy1 = py - y0f, wx1 = px - x0f;
        float wy0 = 1.f - wy1, wx0 = 1.f - wx1;
        float y1f = y0f + 1.f, x1f = x0f + 1.f;
        bool vy0 = (y0f >= 0.f) && (y0f <= 63.f);
        bool vy1 = (y1f >= 0.f) && (y1f <= 63.f);
        bool vx0 = (x0f >= 0.f) && (x0f <= 63.f);
        bool vx1 = (x1f >= 0.f) && (x1f <= 63.f);
        int iy0 = (int)fminf(fmaxf(y0f, 0.f), 63.f);
        int iy1 = (int)fminf(fmaxf(y1f, 0.f), 63.f);
        int ix0 = (int)fminf(fmaxf(x0f, 0.f), 63.f);
        int ix1 = (int)fminf(fmaxf(x1f, 0.f), 63.f);
        i00[e] = iy0 * 64 + ix0; i01[e] = iy0 * 64 + ix1;
        i10[e] = iy1 * 64 + ix0; i11[e] = iy1 * 64 + ix1;
        c00[e] = (vy0 && vx0) ? wy0 * wx0 : 0.f;
        c01[e] = (vy0 && vx1) ? wy0 * wx1 : 0.f;
        c10[e] = (vy1 && vx0) ? wy1 * wx0 : 0.f;
        c11[e] = (vy1 && vx1) ? wy1 * wx1 : 0.f;
    }

    float acc[8][8];
    #pragma unroll
    for (int j = 0; j < 8; ++j)
        #pragma unroll
        for (int i = 0; i < 8; ++i) acc[j][i] = 0.f;

    int og = t >> 3, pg = t & 7;      // o = og*8+j (8 per thread), p = pg*8+i
    const float* hb = h + (size_t)b * C_ * HW_;
    __syncthreads();

    for (int c = 0; c < C_; ++c) {
        const float* wc = wt + (size_t)c * KK_ * C_;
        #pragma unroll
        for (int i = 0; i < KK_; ++i) wlds[t + i * 256] = wc[t + i * 256];
        const float* hp = hb + (size_t)c * HW_;
        for (int e = t; e < 576; e += 256) {
            slds[e] = c00[e] * hp[i00[e]] + c01[e] * hp[i01[e]]
                    + c10[e] * hp[i10[e]] + c11[e] * hp[i11[e]];
        }
        __syncthreads();
        #pragma unroll
        for (int k = 0; k < KK_; ++k) {
            float4 w0 = *(const float4*)&wlds[k * 256 + og * 8];
            float4 w1 = *(const float4*)&wlds[k * 256 + og * 8 + 4];
            float4 s0 = *(const float4*)&slds[k * 64 + pg * 8];
            float4 s1 = *(const float4*)&slds[k * 64 + pg * 8 + 4];
            float wv[8] = {w0.x, w0.y, w0.z, w0.w, w1.x, w1.y, w1.z, w1.w};
            float sv[8] = {s0.x, s0.y, s0.z, s0.w, s1.x, s1.y, s1.z, s1.w};
            #pragma unroll
            for (int j = 0; j < 8; ++j)
                #pragma unroll
                for (int i = 0; i < 8; ++i)
                    acc[j][i] = fmaf(wv[j], sv[i], acc[j][i]);
        }
        __syncthreads();
    }

    #pragma unroll
    for (int j = 0; j < 8; ++j) {
        int o = og * 8 + j;
        float bo = bias[o];
        size_t obase = ((size_t)(b * C_ + o)) * HW_ + row * 64 + pg * 8;
        #pragma unroll
        for (int i = 0; i < 8; ++i) {
            float v = acc[j][i] + bo;
            if (resid) v += resid[obase + i];
            out[obase + i] = v;
        }
    }
}

// ---------------------------------------------------------------------------
extern "C" void kernel_launch(void* const* d_in, const int* in_sizes, int n_in,
                              void* d_out, int out_size, void* d_ws, size_t ws_size,
                              hipStream_t stream)
{
    const float* x     = (const float*)d_in[0];
    const float* gn1_g = (const float*)d_in[1];
    const float* gn1_b = (const float*)d_in[2];
    const float* dw1   = (const float*)d_in[3];
    const float* pw1   = (const float*)d_in[4];
    const float* pwb1  = (const float*)d_in[5];
    const float* w1    = (const float*)d_in[6];
    const float* b1    = (const float*)d_in[7];
    const float* gn2_g = (const float*)d_in[8];
    const float* gn2_b = (const float*)d_in[9];
    const float* dw2   = (const float*)d_in[10];
    const float* pw2   = (const float*)d_in[11];
    const float* pwb2  = (const float*)d_in[12];
    const float* w2    = (const float*)d_in[13];
    const float* b2    = (const float*)d_in[14];
    float* out = (float*)d_out;

    float* ws   = (float*)d_ws;
    float* hbuf = ws;                       // 4,194,304 floats
    float* fy   = ws + 4194304;             // 4,194,304 (f, then y1, then f2)
    float* offb = ws + 8388608;             // 294,912
    float* wt1  = ws + 8683520;             // 589,824
    float* wt2  = ws + 9273344;             // 589,824  (total ~39.5 MB)

    wt_kernel<<<2304, 256, 0, stream>>>(w1, wt1);
    wt_kernel<<<2304, 256, 0, stream>>>(w2, wt2);

    // layer 1
    gn_relu_kernel<<<B_ * NG_, 256, 0, stream>>>(x, gn1_g, gn1_b, hbuf);
    dw7_kernel<<<B_ * C_, 256, 0, stream>>>(hbuf, dw1, fy);
    pw_off_kernel<<<B_ * HW_ / 256, 256, 0, stream>>>(fy, pw1, pwb1, offb);
    deform_kernel<<<B_ * H_, 256, 0, stream>>>(hbuf, offb, wt1, b1, nullptr, fy);

    // layer 2 (+ residual x)
    gn_relu_kernel<<<B_ * NG_, 256, 0, stream>>>(fy, gn2_g, gn2_b, hbuf);
    dw7_kernel<<<B_ * C_, 256, 0, stream>>>(hbuf, dw2, fy);
    pw_off_kernel<<<B_ * HW_ / 256, 256, 0, stream>>>(fy, pw2, pwb2, offb);
    deform_kernel<<<B_ * H_, 256, 0, stream>>>(hbuf, offb, wt2, b2, x, out);
}

// Round 2
// 560.549 us; speedup vs baseline: 2.2507x; 2.2507x over previous
//
#include <hip/hip_runtime.h>

#define B_    4
#define C_    256
#define H_    64
#define W_    64
#define HW_   4096
#define NG_   32
#define CPG_  8
#define KK_   9
#define NOFF_ 18

typedef __attribute__((ext_vector_type(8))) short short8;
typedef __attribute__((ext_vector_type(4))) float floatx4;

static __device__ __forceinline__ short f2bf(float f) {
    union { float f; unsigned u; } v; v.f = f;
    unsigned r = v.u + 0x7fff + ((v.u >> 16) & 1);   // RNE
    return (short)(r >> 16);
}

// ---------------------------------------------------------------------------
// K1: GroupNorm (32 groups) + ReLU. One block per (b, group).
// ---------------------------------------------------------------------------
__global__ __launch_bounds__(256) void gn_relu_kernel(
    const float* __restrict__ in, const float* __restrict__ gamma,
    const float* __restrict__ beta, float* __restrict__ out)
{
    int b = blockIdx.x >> 5;
    int g = blockIdx.x & 31;
    const int N = CPG_ * HW_;              // 32768
    size_t base = ((size_t)(b * C_ + g * CPG_)) * HW_;
    const float4* in4 = (const float4*)(in + base);
    int t = threadIdx.x;

    float s = 0.f, ss = 0.f;
    for (int i = t; i < N / 4; i += 256) {
        float4 v = in4[i];
        s  += v.x + v.y + v.z + v.w;
        ss += v.x * v.x + v.y * v.y + v.z * v.z + v.w * v.w;
    }
    #pragma unroll
    for (int off = 32; off > 0; off >>= 1) {
        s  += __shfl_down(s, off, 64);
        ss += __shfl_down(ss, off, 64);
    }
    __shared__ float red[16];
    __shared__ float sh_rs, sh_m;
    int wid = t >> 6;
    if ((t & 63) == 0) { red[wid] = s; red[8 + wid] = ss; }
    __syncthreads();
    if (t == 0) {
        float S  = red[0] + red[1] + red[2] + red[3];
        float SS = red[8] + red[9] + red[10] + red[11];
        float m = S / (float)N;
        float var = SS / (float)N - m * m;
        sh_rs = rsqrtf(var + 1e-5f);
        sh_m = m;
    }
    __syncthreads();
    float rs = sh_rs, m = sh_m;
    float4* out4 = (float4*)(out + base);
    for (int i = t; i < N / 4; i += 256) {
        int ch = g * CPG_ + (i >> 10);
        float ga = gamma[ch] * rs;
        float be = beta[ch] - m * ga;
        float4 v = in4[i];
        float4 o;
        o.x = fmaxf(fmaf(v.x, ga, be), 0.f);
        o.y = fmaxf(fmaf(v.y, ga, be), 0.f);
        o.z = fmaxf(fmaf(v.z, ga, be), 0.f);
        o.w = fmaxf(fmaf(v.w, ga, be), 0.f);
        out4[i] = o;
    }
}

// ---------------------------------------------------------------------------
// K2: depthwise 7x7 SAME conv. One block per (b,c) plane, LDS halo tile.
// ---------------------------------------------------------------------------
__global__ __launch_bounds__(256) void dw7_kernel(
    const float* __restrict__ in, const float* __restrict__ dwk,
    float* __restrict__ out)
{
    int plane = blockIdx.x;
    int c = plane & (C_ - 1);
    const float* src = in + (size_t)plane * HW_;
    float* dst = out + (size_t)plane * HW_;
    __shared__ float tile[70 * 72];
    __shared__ float wk[49];
    int t = threadIdx.x;
    if (t < 49) wk[t] = dwk[c * 49 + t];
    for (int i = t; i < 70 * 72; i += 256) tile[i] = 0.f;
    __syncthreads();
    for (int i = t; i < HW_; i += 256) {
        int y = i >> 6, x = i & 63;
        tile[(y + 3) * 72 + (x + 3)] = src[i];
    }
    __syncthreads();
    for (int i = t; i < HW_; i += 256) {
        int y = i >> 6, x = i & 63;
        float acc = 0.f;
        #pragma unroll
        for (int dy = 0; dy < 7; ++dy)
            #pragma unroll
            for (int dx = 0; dx < 7; ++dx)
                acc = fmaf(tile[(y + dy) * 72 + x + dx], wk[dy * 7 + dx], acc);
        dst[i] = acc;
    }
}

// ---------------------------------------------------------------------------
// K3: pointwise 256->18 conv + bias.
// ---------------------------------------------------------------------------
__global__ __launch_bounds__(256) void pw_off_kernel(
    const float* __restrict__ f, const float* __restrict__ pw,
    const float* __restrict__ pwb, float* __restrict__ off)
{
    int b = blockIdx.x >> 4;
    int pbase = (blockIdx.x & 15) * 256;
    __shared__ float wl[NOFF_ * C_];
    int t = threadIdx.x;
    for (int i = t; i < NOFF_ * C_; i += 256) wl[i] = pw[i];
    __syncthreads();
    int p = pbase + t;
    const float* fb = f + (size_t)b * C_ * HW_ + p;
    float acc[NOFF_];
    #pragma unroll
    for (int o = 0; o < NOFF_; ++o) acc[o] = pwb[o];
    for (int c = 0; c < C_; ++c) {
        float v = fb[(size_t)c * HW_];
        #pragma unroll
        for (int o = 0; o < NOFF_; ++o)
            acc[o] = fmaf(wl[o * C_ + c], v, acc[o]);
    }
    float* ob = off + (size_t)b * NOFF_ * HW_ + p;
    #pragma unroll
    for (int o = 0; o < NOFF_; ++o) ob[(size_t)o * HW_] = acc[o];
}

// ---------------------------------------------------------------------------
// K4: pack w[o][c][3][3] (fp32) into fragment-major bf16 for direct A-frag
// global loads. Fragment id = (slab, ot): slab = k*8+cc (72 slabs of K=32),
// ot = o-tile (16). Within fragment: lane holds A[o = ot*16+(lane&15)]
// [c = cc*32+(lane>>4)*8+j], j=0..7 contiguous -> 16B per lane.
// ---------------------------------------------------------------------------
__global__ __launch_bounds__(256) void wpack_kernel(
    const float* __restrict__ w, short* __restrict__ wp)
{
    int idx = blockIdx.x * 256 + threadIdx.x;   // 589824 total
    int j    = idx & 7;
    int lane = (idx >> 3) & 63;
    int ot   = (idx >> 9) & 15;
    int slab = idx >> 13;                        // 0..71
    int k = slab >> 3, cc = slab & 7;
    int o = ot * 16 + (lane & 15);
    int c = cc * 32 + (lane >> 4) * 8 + j;
    wp[idx] = f2bf(w[(size_t)(o * C_ + c) * KK_ + k]);
}

// ---------------------------------------------------------------------------
// K5: fused deformable gather + bf16-MFMA einsum + bias (+residual).
// One block (256 thr = 4 waves) per (b,row). Bilinear corner idx/weights
// precomputed per (k,pixel) with OOB folded into zero weights. K dim ordered
// (k,c): 72 slabs of 32 channels. Per slab: 256 threads gather S[32c][64p]
// into a fragment-major, XOR-swizzled 4KB LDS buffer (double-buffered, one
// barrier/slab); each wave computes 64o x 64p via 16 mfma_f32_16x16x32_bf16.
// ---------------------------------------------------------------------------
__global__ __launch_bounds__(256) void deform_mfma_kernel(
    const float* __restrict__ h, const float* __restrict__ off,
    const short* __restrict__ wp, const float* __restrict__ bias,
    const float* __restrict__ resid, float* __restrict__ out)
{
    int b = blockIdx.x >> 6;
    int row = blockIdx.x & 63;
    __shared__ int   i00[576], i01[576], i10[576], i11[576];
    __shared__ float c00[576], c01[576], c10[576], c11[576];
    __shared__ __align__(16) short sbuf[2][2048];   // 2 x 4KB S-slab
    int t = threadIdx.x;

    for (int e = t; e < 576; e += 256) {
        int k = e >> 6, p = e & 63;
        float offy = off[((size_t)(b * NOFF_) + 2 * k) * HW_ + row * 64 + p];
        float offx = off[((size_t)(b * NOFF_) + 2 * k + 1) * HW_ + row * 64 + p];
        float py = (float)row + (float)(k / 3 - 1) + offy;
        float px = (float)p   + (float)(k % 3 - 1) + offx;
        float y0f = floorf(py), x0f = floorf(px);
        float wy1 = py - y0f, wx1 = px - x0f;
        float wy0 = 1.f - wy1, wx0 = 1.f - wx1;
        float y1f = y0f + 1.f, x1f = x0f + 1.f;
        bool vy0 = (y0f >= 0.f) && (y0f <= 63.f);
        bool vy1 = (y1f >= 0.f) && (y1f <= 63.f);
        bool vx0 = (x0f >= 0.f) && (x0f <= 63.f);
        bool vx1 = (x1f >= 0.f) && (x1f <= 63.f);
        int iy0 = (int)fminf(fmaxf(y0f, 0.f), 63.f);
        int iy1 = (int)fminf(fmaxf(y1f, 0.f), 63.f);
        int ix0 = (int)fminf(fmaxf(x0f, 0.f), 63.f);
        int ix1 = (int)fminf(fmaxf(x1f, 0.f), 63.f);
        i00[e] = iy0 * 64 + ix0; i01[e] = iy0 * 64 + ix1;
        i10[e] = iy1 * 64 + ix0; i11[e] = iy1 * 64 + ix1;
        c00[e] = (vy0 && vx0) ? wy0 * wx0 : 0.f;
        c01[e] = (vy0 && vx1) ? wy0 * wx1 : 0.f;
        c10[e] = (vy1 && vx0) ? wy1 * wx0 : 0.f;
        c11[e] = (vy1 && vx1) ? wy1 * wx1 : 0.f;
    }

    int wv = t >> 6, lane = t & 63;
    int pq = lane >> 4, pr = lane & 15;
    const float* hb = h + (size_t)b * C_ * HW_;

    // staging: thread t -> pixel p = t>>2, c-block cb = t&3 (8 channels)
    int sp = t >> 2, scb = t & 3;
    int su = sp * 4 + (scb ^ (sp & 3));          // swizzled 16B-unit index

    auto stage = [&](int s, short* buf) {
        int k = s >> 3, cc = s & 7;
        int e = k * 64 + sp;
        float w00 = c00[e], w01 = c01[e], w10 = c10[e], w11 = c11[e];
        int a00 = i00[e], a01 = i01[e], a10 = i10[e], a11 = i11[e];
        const float* hp = hb + (size_t)(cc * 32 + scb * 8) * HW_;
        short8 v8;
        #pragma unroll
        for (int j = 0; j < 8; ++j) {
            float v = w00 * hp[a00] + w01 * hp[a01]
                    + w10 * hp[a10] + w11 * hp[a11];
            v8[j] = f2bf(v);
            hp += HW_;
        }
        *(short8*)&buf[su * 8] = v8;
    };

    floatx4 acc[4][4];
    #pragma unroll
    for (int i = 0; i < 4; ++i)
        #pragma unroll
        for (int pt = 0; pt < 4; ++pt)
            acc[i][pt] = (floatx4){0.f, 0.f, 0.f, 0.f};

    __syncthreads();                 // coeffs ready
    stage(0, sbuf[0]);
    __syncthreads();

    const short8* wp8 = (const short8*)wp;
    for (int s = 0; s < 72; ++s) {
        // A fragments: direct coalesced global (L2-resident), 16B/lane
        const short8* wa = wp8 + (size_t)(s * 16 + wv * 4) * 64 + lane;
        short8 af0 = wa[0], af1 = wa[64], af2 = wa[128], af3 = wa[192];
        if (s + 1 < 72) stage(s + 1, sbuf[(s + 1) & 1]);
        short* buf = sbuf[s & 1];
        #pragma unroll
        for (int pt = 0; pt < 4; ++pt) {
            int p = pt * 16 + pr;
            int u = p * 4 + (pq ^ (p & 3));
            short8 bfv = *(short8*)&buf[u * 8];
            acc[0][pt] = __builtin_amdgcn_mfma_f32_16x16x32_bf16(af0, bfv, acc[0][pt], 0, 0, 0);
            acc[1][pt] = __builtin_amdgcn_mfma_f32_16x16x32_bf16(af1, bfv, acc[1][pt], 0, 0, 0);
            acc[2][pt] = __builtin_amdgcn_mfma_f32_16x16x32_bf16(af2, bfv, acc[2][pt], 0, 0, 0);
            acc[3][pt] = __builtin_amdgcn_mfma_f32_16x16x32_bf16(af3, bfv, acc[3][pt], 0, 0, 0);
        }
        __syncthreads();
    }

    // epilogue: D layout col = lane&15 (pixel), row = (lane>>4)*4 + reg (o)
    #pragma unroll
    for (int i = 0; i < 4; ++i) {
        #pragma unroll
        for (int r = 0; r < 4; ++r) {
            int o = (wv * 4 + i) * 16 + pq * 4 + r;
            float bo = bias[o];
            size_t obase = ((size_t)(b * C_ + o)) * HW_ + row * 64 + pr;
            #pragma unroll
            for (int pt = 0; pt < 4; ++pt) {
                float v = acc[i][pt][r] + bo;
                if (resid) v += resid[obase + pt * 16];
                out[obase + pt * 16] = v;
            }
        }
    }
}

// ---------------------------------------------------------------------------
extern "C" void kernel_launch(void* const* d_in, const int* in_sizes, int n_in,
                              void* d_out, int out_size, void* d_ws, size_t ws_size,
                              hipStream_t stream)
{
    const float* x     = (const float*)d_in[0];
    const float* gn1_g = (const float*)d_in[1];
    const float* gn1_b = (const float*)d_in[2];
    const float* dw1   = (const float*)d_in[3];
    const float* pw1   = (const float*)d_in[4];
    const float* pwb1  = (const float*)d_in[5];
    const float* w1    = (const float*)d_in[6];
    const float* b1    = (const float*)d_in[7];
    const float* gn2_g = (const float*)d_in[8];
    const float* gn2_b = (const float*)d_in[9];
    const float* dw2   = (const float*)d_in[10];
    const float* pw2   = (const float*)d_in[11];
    const float* pwb2  = (const float*)d_in[12];
    const float* w2    = (const float*)d_in[13];
    const float* b2    = (const float*)d_in[14];
    float* out = (float*)d_out;

    float* ws   = (float*)d_ws;
    float* hbuf = ws;                       // 4,194,304 floats
    float* fy   = ws + 4194304;             // 4,194,304
    float* offb = ws + 8388608;             // 294,912
    short* wp1  = (short*)(ws + 8683520);   // 589,824 bf16 (294,912 floats)
    short* wp2  = (short*)(ws + 8978432);   // 589,824 bf16

    wpack_kernel<<<2304, 256, 0, stream>>>(w1, wp1);
    wpack_kernel<<<2304, 256, 0, stream>>>(w2, wp2);

    // layer 1
    gn_relu_kernel<<<B_ * NG_, 256, 0, stream>>>(x, gn1_g, gn1_b, hbuf);
    dw7_kernel<<<B_ * C_, 256, 0, stream>>>(hbuf, dw1, fy);
    pw_off_kernel<<<B_ * HW_ / 256, 256, 0, stream>>>(fy, pw1, pwb1, offb);
    deform_mfma_kernel<<<B_ * H_, 256, 0, stream>>>(hbuf, offb, wp1, b1, nullptr, fy);

    // layer 2 (+ residual x)
    gn_relu_kernel<<<B_ * NG_, 256, 0, stream>>>(fy, gn2_g, gn2_b, hbuf);
    dw7_kernel<<<B_ * C_, 256, 0, stream>>>(hbuf, dw2, fy);
    pw_off_kernel<<<B_ * HW_ / 256, 256, 0, stream>>>(fy, pw2, pwb2, offb);
    deform_mfma_kernel<<<B_ * H_, 256, 0, stream>>>(hbuf, offb, wp2, b2, x, out);
}

// Round 3
// 433.827 us; speedup vs baseline: 2.9082x; 1.2921x over previous
//
#include <hip/hip_runtime.h>

#define B_    4
#define C_    256
#define H_    64
#define W_    64
#define HW_   4096
#define NG_   32
#define CPG_  8
#define KK_   9
#define NOFF_ 18

typedef __attribute__((ext_vector_type(8))) short short8;
typedef __attribute__((ext_vector_type(4))) short short4v;
typedef __attribute__((ext_vector_type(4))) float floatx4;

static __device__ __forceinline__ short f2bf(float f) {
    union { float f; unsigned u; } v; v.f = f;
    unsigned r = v.u + 0x7fff + ((v.u >> 16) & 1);   // RNE
    return (short)(r >> 16);
}
static __device__ __forceinline__ float bf2f(short s) {
    union { unsigned u; float f; } v;
    v.u = ((unsigned)(unsigned short)s) << 16;
    return v.f;
}

// ---------------------------------------------------------------------------
// K1: GroupNorm (32 groups) + ReLU, fp32 in -> bf16 out.
// One block per (b, group) = 8 contiguous channels.
// ---------------------------------------------------------------------------
__global__ __launch_bounds__(256) void gn_relu_kernel(
    const float* __restrict__ in, const float* __restrict__ gamma,
    const float* __restrict__ beta, short* __restrict__ outb)
{
    int b = blockIdx.x >> 5;
    int g = blockIdx.x & 31;
    const int N = CPG_ * HW_;              // 32768
    size_t base = ((size_t)(b * C_ + g * CPG_)) * HW_;
    const float4* in4 = (const float4*)(in + base);
    int t = threadIdx.x;

    float s = 0.f, ss = 0.f;
    for (int i = t; i < N / 4; i += 256) {
        float4 v = in4[i];
        s  += v.x + v.y + v.z + v.w;
        ss += v.x * v.x + v.y * v.y + v.z * v.z + v.w * v.w;
    }
    #pragma unroll
    for (int off = 32; off > 0; off >>= 1) {
        s  += __shfl_down(s, off, 64);
        ss += __shfl_down(ss, off, 64);
    }
    __shared__ float red[16];
    __shared__ float sh_rs, sh_m;
    int wid = t >> 6;
    if ((t & 63) == 0) { red[wid] = s; red[8 + wid] = ss; }
    __syncthreads();
    if (t == 0) {
        float S  = red[0] + red[1] + red[2] + red[3];
        float SS = red[8] + red[9] + red[10] + red[11];
        float m = S / (float)N;
        float var = SS / (float)N - m * m;
        sh_rs = rsqrtf(var + 1e-5f);
        sh_m = m;
    }
    __syncthreads();
    float rs = sh_rs, m = sh_m;
    short4v* out4 = (short4v*)(outb + base);
    for (int i = t; i < N / 4; i += 256) {
        int ch = g * CPG_ + (i >> 10);
        float ga = gamma[ch] * rs;
        float be = beta[ch] - m * ga;
        float4 v = in4[i];
        short4v o;
        o.x = f2bf(fmaxf(fmaf(v.x, ga, be), 0.f));
        o.y = f2bf(fmaxf(fmaf(v.y, ga, be), 0.f));
        o.z = f2bf(fmaxf(fmaf(v.z, ga, be), 0.f));
        o.w = f2bf(fmaxf(fmaf(v.w, ga, be), 0.f));
        out4[i] = o;
    }
}

// ---------------------------------------------------------------------------
// K2: depthwise 7x7 SAME conv, bf16 in -> fp32 out. One block per (b,c)
// plane, halo tile in LDS (fp32 after conversion).
// ---------------------------------------------------------------------------
__global__ __launch_bounds__(256) void dw7_kernel(
    const short* __restrict__ in, const float* __restrict__ dwk,
    float* __restrict__ out)
{
    int plane = blockIdx.x;
    int c = plane & (C_ - 1);
    const short* src = in + (size_t)plane * HW_;
    float* dst = out + (size_t)plane * HW_;
    __shared__ float tile[70 * 72];
    __shared__ float wk[49];
    int t = threadIdx.x;
    if (t < 49) wk[t] = dwk[c * 49 + t];
    for (int i = t; i < 70 * 72; i += 256) tile[i] = 0.f;
    __syncthreads();
    const short4v* src4 = (const short4v*)src;
    for (int i = t; i < HW_ / 4; i += 256) {
        short4v v = src4[i];
        int y = i >> 4, x = (i & 15) * 4;
        float* tp = &tile[(y + 3) * 72 + (x + 3)];
        tp[0] = bf2f(v.x); tp[1] = bf2f(v.y);
        tp[2] = bf2f(v.z); tp[3] = bf2f(v.w);
    }
    __syncthreads();
    for (int i = t; i < HW_; i += 256) {
        int y = i >> 6, x = i & 63;
        float acc = 0.f;
        #pragma unroll
        for (int dy = 0; dy < 7; ++dy)
            #pragma unroll
            for (int dx = 0; dx < 7; ++dx)
                acc = fmaf(tile[(y + dy) * 72 + x + dx], wk[dy * 7 + dx], acc);
        dst[i] = acc;
    }
}

// ---------------------------------------------------------------------------
// K3: pointwise 256->18 conv + bias. One block per (b,row): 64 px, 4-way
// channel split (thread = (cs, px)), LDS partials + reduction. Grid = 256.
// ---------------------------------------------------------------------------
__global__ __launch_bounds__(256) void pw_off_kernel(
    const float* __restrict__ f, const float* __restrict__ pw,
    const float* __restrict__ pwb, float* __restrict__ off)
{
    int b = blockIdx.x >> 6;
    int rowblk = blockIdx.x & 63;
    __shared__ float wl[NOFF_ * C_];        // 18 KB
    __shared__ float part[4 * NOFF_ * 64];  // 18 KB
    int t = threadIdx.x;
    for (int i = t; i < NOFF_ * C_; i += 256) wl[i] = pw[i];
    __syncthreads();
    int px = t & 63, cs = t >> 6;
    int p = rowblk * 64 + px;
    const float* fb = f + (size_t)b * C_ * HW_ + (size_t)(cs * 64) * HW_ + p;
    float acc[NOFF_];
    #pragma unroll
    for (int o = 0; o < NOFF_; ++o) acc[o] = 0.f;
    for (int i = 0; i < 64; ++i) {
        float v = fb[(size_t)i * HW_];
        const float* wrow = &wl[cs * 64 + i];
        #pragma unroll
        for (int o = 0; o < NOFF_; ++o)
            acc[o] = fmaf(wrow[o * C_], v, acc[o]);
    }
    #pragma unroll
    for (int o = 0; o < NOFF_; ++o)
        part[(cs * NOFF_ + o) * 64 + px] = acc[o];
    __syncthreads();
    for (int idx = t; idx < NOFF_ * 64; idx += 256) {
        int o = idx >> 6, q = idx & 63;
        float sum = part[o * 64 + q] + part[(NOFF_ + o) * 64 + q]
                  + part[(2 * NOFF_ + o) * 64 + q] + part[(3 * NOFF_ + o) * 64 + q]
                  + pwb[o];
        off[((size_t)(b * NOFF_) + o) * HW_ + rowblk * 64 + q] = sum;
    }
}

// ---------------------------------------------------------------------------
// K4: pack w[o][c][3][3] (fp32) into fragment-major bf16.
// Fragment id = (slab, ot): slab = k*8+cc (72 slabs of K=32), ot = o/16.
// Lane holds A[o = ot*16+(lane&15)][c = cc*32+(lane>>4)*8+j], j contiguous.
// ---------------------------------------------------------------------------
__global__ __launch_bounds__(256) void wpack_kernel(
    const float* __restrict__ w, short* __restrict__ wp)
{
    int idx = blockIdx.x * 256 + threadIdx.x;   // 589824 total
    int j    = idx & 7;
    int lane = (idx >> 3) & 63;
    int ot   = (idx >> 9) & 15;
    int slab = idx >> 13;                        // 0..71
    int k = slab >> 3, cc = slab & 7;
    int o = ot * 16 + (lane & 15);
    int c = cc * 32 + (lane >> 4) * 8 + j;
    wp[idx] = f2bf(w[(size_t)(o * C_ + c) * KK_ + k]);
}

// ---------------------------------------------------------------------------
// K5: fused deformable gather + bf16-MFMA einsum + bias (+residual).
// 1024 threads (16 waves) per (b,row). K = 72 slabs of 32ch, staged in
// groups of 4 slabs (18 barriers). Staging thread t: px=t&63 (consecutive
// lanes -> consecutive gathered pixels), cb=(t>>6)&3, sl=t>>8.
// XOR swizzle (px+(px>>2))&3 is conflict-free for write AND read b128.
// Each wave owns one 16-o tile: 4 acc tiles, 16 MFMA/group.
// ---------------------------------------------------------------------------
__global__ __launch_bounds__(1024) void deform_mfma_kernel(
    const short* __restrict__ h, const float* __restrict__ off,
    const short* __restrict__ wp, const float* __restrict__ bias,
    const float* __restrict__ resid, float* __restrict__ out)
{
    int b = blockIdx.x >> 6;
    int row = blockIdx.x & 63;
    __shared__ int   i00[576], i01[576], i10[576], i11[576];
    __shared__ float c00[576], c01[576], c10[576], c11[576];
    __shared__ __align__(16) short sbuf[2][8192];   // 2 x 16KB (4 slabs)
    int t = threadIdx.x;

    for (int e = t; e < 576; e += 1024) {
        int k = e >> 6, p = e & 63;
        float offy = off[((size_t)(b * NOFF_) + 2 * k) * HW_ + row * 64 + p];
        float offx = off[((size_t)(b * NOFF_) + 2 * k + 1) * HW_ + row * 64 + p];
        float py = (float)row + (float)(k / 3 - 1) + offy;
        float px = (float)p   + (float)(k % 3 - 1) + offx;
        float y0f = floorf(py), x0f = floorf(px);
        float wy1 = py - y0f, wx1 = px - x0f;
        float wy0 = 1.f - wy1, wx0 = 1.f - wx1;
        float y1f = y0f + 1.f, x1f = x0f + 1.f;
        bool vy0 = (y0f >= 0.f) && (y0f <= 63.f);
        bool vy1 = (y1f >= 0.f) && (y1f <= 63.f);
        bool vx0 = (x0f >= 0.f) && (x0f <= 63.f);
        bool vx1 = (x1f >= 0.f) && (x1f <= 63.f);
        int iy0 = (int)fminf(fmaxf(y0f, 0.f), 63.f);
        int iy1 = (int)fminf(fmaxf(y1f, 0.f), 63.f);
        int ix0 = (int)fminf(fmaxf(x0f, 0.f), 63.f);
        int ix1 = (int)fminf(fmaxf(x1f, 0.f), 63.f);
        i00[e] = iy0 * 64 + ix0; i01[e] = iy0 * 64 + ix1;
        i10[e] = iy1 * 64 + ix0; i11[e] = iy1 * 64 + ix1;
        c00[e] = (vy0 && vx0) ? wy0 * wx0 : 0.f;
        c01[e] = (vy0 && vx1) ? wy0 * wx1 : 0.f;
        c10[e] = (vy1 && vx0) ? wy1 * wx0 : 0.f;
        c11[e] = (vy1 && vx1) ? wy1 * wx1 : 0.f;
    }

    int wv = t >> 6;                 // wave id = o-tile (0..15)
    int lane = t & 63;
    int pq = lane >> 4, pr = lane & 15;

    // staging decomposition
    int spx = t & 63, scb = (t >> 6) & 3, ssl = t >> 8;
    const short* hb = h + (size_t)b * C_ * HW_;

    auto stage = [&](int g, int bi) {
        int s = 4 * g + ssl;
        int k = s >> 3, cc = s & 7;
        int e = k * 64 + spx;
        float w00 = c00[e], w01 = c01[e], w10 = c10[e], w11 = c11[e];
        int a00 = i00[e], a01 = i01[e], a10 = i10[e], a11 = i11[e];
        const short* hp = hb + (size_t)(cc * 32 + scb * 8) * HW_;
        short8 v8;
        #pragma unroll
        for (int j = 0; j < 8; ++j) {
            float v = w00 * bf2f(hp[a00]) + w01 * bf2f(hp[a01])
                    + w10 * bf2f(hp[a10]) + w11 * bf2f(hp[a11]);
            v8[j] = f2bf(v);
            hp += HW_;
        }
        int u = spx * 4 + (scb ^ ((spx + (spx >> 2)) & 3));
        *(short8*)&sbuf[bi][ssl * 2048 + u * 8] = v8;
    };

    floatx4 acc[4];
    #pragma unroll
    for (int pt = 0; pt < 4; ++pt) acc[pt] = (floatx4){0.f, 0.f, 0.f, 0.f};

    __syncthreads();                 // coeff tables ready
    stage(0, 0);
    __syncthreads();

    const short8* wp8 = (const short8*)wp;
    // precompute B-frag LDS unit indices (per pt, same for all slabs)
    int ub[4];
    #pragma unroll
    for (int pt = 0; pt < 4; ++pt) {
        int px2 = pt * 16 + pr;
        ub[pt] = px2 * 4 + (pq ^ ((px2 + (px2 >> 2)) & 3));
    }

    for (int g = 0; g < 18; ++g) {
        short8 af[4];
        #pragma unroll
        for (int sl = 0; sl < 4; ++sl)
            af[sl] = wp8[(size_t)((4 * g + sl) * 16 + wv) * 64 + lane];
        if (g + 1 < 18) stage(g + 1, (g + 1) & 1);
        const short* sb = sbuf[g & 1];
        #pragma unroll
        for (int sl = 0; sl < 4; ++sl) {
            #pragma unroll
            for (int pt = 0; pt < 4; ++pt) {
                short8 bfv = *(const short8*)&sb[sl * 2048 + ub[pt] * 8];
                acc[pt] = __builtin_amdgcn_mfma_f32_16x16x32_bf16(
                    af[sl], bfv, acc[pt], 0, 0, 0);
            }
        }
        __syncthreads();
    }

    // epilogue: D layout col=lane&15 (pixel), row=(lane>>4)*4+reg (o-local)
    #pragma unroll
    for (int r = 0; r < 4; ++r) {
        int o = wv * 16 + pq * 4 + r;
        float bo = bias[o];
        size_t obase = ((size_t)(b * C_ + o)) * HW_ + row * 64 + pr;
        #pragma unroll
        for (int pt = 0; pt < 4; ++pt) {
            float v = acc[pt][r] + bo;
            if (resid) v += resid[obase + pt * 16];
            out[obase + pt * 16] = v;
        }
    }
}

// ---------------------------------------------------------------------------
extern "C" void kernel_launch(void* const* d_in, const int* in_sizes, int n_in,
                              void* d_out, int out_size, void* d_ws, size_t ws_size,
                              hipStream_t stream)
{
    const float* x     = (const float*)d_in[0];
    const float* gn1_g = (const float*)d_in[1];
    const float* gn1_b = (const float*)d_in[2];
    const float* dw1   = (const float*)d_in[3];
    const float* pw1   = (const float*)d_in[4];
    const float* pwb1  = (const float*)d_in[5];
    const float* w1    = (const float*)d_in[6];
    const float* b1    = (const float*)d_in[7];
    const float* gn2_g = (const float*)d_in[8];
    const float* gn2_b = (const float*)d_in[9];
    const float* dw2   = (const float*)d_in[10];
    const float* pw2   = (const float*)d_in[11];
    const float* pwb2  = (const float*)d_in[12];
    const float* w2    = (const float*)d_in[13];
    const float* b2    = (const float*)d_in[14];
    float* out = (float*)d_out;

    float* ws   = (float*)d_ws;
    float* fy   = ws;                          // 4,194,304 floats (16 MB)
    short* hbf  = (short*)(ws + 4194304);      // 4,194,304 bf16 (8 MB)
    float* offb = ws + 6291456;                // 294,912
    short* wp1  = (short*)(ws + 6586368);      // 589,824 bf16
    short* wp2  = (short*)(ws + 6881280);      // 589,824 bf16

    wpack_kernel<<<2304, 256, 0, stream>>>(w1, wp1);
    wpack_kernel<<<2304, 256, 0, stream>>>(w2, wp2);

    // layer 1
    gn_relu_kernel<<<B_ * NG_, 256, 0, stream>>>(x, gn1_g, gn1_b, hbf);
    dw7_kernel<<<B_ * C_, 256, 0, stream>>>(hbf, dw1, fy);
    pw_off_kernel<<<B_ * H_, 256, 0, stream>>>(fy, pw1, pwb1, offb);
    deform_mfma_kernel<<<B_ * H_, 1024, 0, stream>>>(hbf, offb, wp1, b1, nullptr, fy);

    // layer 2 (+ residual x)
    gn_relu_kernel<<<B_ * NG_, 256, 0, stream>>>(fy, gn2_g, gn2_b, hbf);
    dw7_kernel<<<B_ * C_, 256, 0, stream>>>(hbf, dw2, fy);
    pw_off_kernel<<<B_ * H_, 256, 0, stream>>>(fy, pw2, pwb2, offb);
    deform_mfma_kernel<<<B_ * H_, 1024, 0, stream>>>(hbf, offb, wp2, b2, x, out);
}

// Round 4
// 342.885 us; speedup vs baseline: 3.6795x; 1.2652x over previous
//
#include <hip/hip_runtime.h>

#define B_    4
#define C_    256
#define H_    64
#define W_    64
#define HW_   4096
#define NG_   32
#define CPG_  8
#define KK_   9
#define NOFF_ 18

typedef __attribute__((ext_vector_type(8))) short short8;
typedef __attribute__((ext_vector_type(4))) short short4v;
typedef __attribute__((ext_vector_type(4))) float floatx4;

static __device__ __forceinline__ short f2bf(float f) {
    union { float f; unsigned u; } v; v.f = f;
    unsigned r = v.u + 0x7fff + ((v.u >> 16) & 1);   // RNE
    return (short)(r >> 16);
}
static __device__ __forceinline__ float bf2f(short s) {
    union { unsigned u; float f; } v;
    v.u = ((unsigned)(unsigned short)s) << 16;
    return v.f;
}

// ---------------------------------------------------------------------------
// K1: GroupNorm (32 groups) + ReLU, fp32 in -> bf16 out [C][HW].
// One block per (b, group) = 8 contiguous channels.
// ---------------------------------------------------------------------------
__global__ __launch_bounds__(256) void gn_relu_kernel(
    const float* __restrict__ in, const float* __restrict__ gamma,
    const float* __restrict__ beta, short* __restrict__ outb)
{
    int b = blockIdx.x >> 5;
    int g = blockIdx.x & 31;
    const int N = CPG_ * HW_;              // 32768
    size_t base = ((size_t)(b * C_ + g * CPG_)) * HW_;
    const float4* in4 = (const float4*)(in + base);
    int t = threadIdx.x;

    float s = 0.f, ss = 0.f;
    for (int i = t; i < N / 4; i += 256) {
        float4 v = in4[i];
        s  += v.x + v.y + v.z + v.w;
        ss += v.x * v.x + v.y * v.y + v.z * v.z + v.w * v.w;
    }
    #pragma unroll
    for (int off = 32; off > 0; off >>= 1) {
        s  += __shfl_down(s, off, 64);
        ss += __shfl_down(ss, off, 64);
    }
    __shared__ float red[16];
    __shared__ float sh_rs, sh_m;
    int wid = t >> 6;
    if ((t & 63) == 0) { red[wid] = s; red[8 + wid] = ss; }
    __syncthreads();
    if (t == 0) {
        float S  = red[0] + red[1] + red[2] + red[3];
        float SS = red[8] + red[9] + red[10] + red[11];
        float m = S / (float)N;
        float var = SS / (float)N - m * m;
        sh_rs = rsqrtf(var + 1e-5f);
        sh_m = m;
    }
    __syncthreads();
    float rs = sh_rs, m = sh_m;
    short4v* out4 = (short4v*)(outb + base);
    for (int i = t; i < N / 4; i += 256) {
        int ch = g * CPG_ + (i >> 10);
        float ga = gamma[ch] * rs;
        float be = beta[ch] - m * ga;
        float4 v = in4[i];
        short4v o;
        o.x = f2bf(fmaxf(fmaf(v.x, ga, be), 0.f));
        o.y = f2bf(fmaxf(fmaf(v.y, ga, be), 0.f));
        o.z = f2bf(fmaxf(fmaf(v.z, ga, be), 0.f));
        o.w = f2bf(fmaxf(fmaf(v.w, ga, be), 0.f));
        out4[i] = o;
    }
}

// ---------------------------------------------------------------------------
// K1b: transpose bf16 [C][HW] -> [HW][C]. Thread = (b, ch-octet, px).
// 8 coalesced ushort loads (128B/wave each) + one 16B store per thread.
// ---------------------------------------------------------------------------
__global__ __launch_bounds__(256) void transpose_kernel(
    const short* __restrict__ hbf, short* __restrict__ hbt)
{
    int idx = blockIdx.x * 256 + threadIdx.x;   // 524288 total -> 2048 blocks
    int px = idx & 4095;
    int co = (idx >> 12) & 31;
    int b  = idx >> 17;
    const short* src = hbf + ((size_t)(b * C_ + co * 8)) * HW_ + px;
    short8 v;
    #pragma unroll
    for (int j = 0; j < 8; ++j) v[j] = src[(size_t)j * HW_];
    *(short8*)(hbt + ((size_t)b * HW_ + px) * C_ + co * 8) = v;
}

// ---------------------------------------------------------------------------
// K2: depthwise 7x7 SAME conv, bf16 in -> fp32 out. One block per (b,c)
// plane. Each thread computes a 1x4 output strip: 3 ds_read_b128 per tap
// row (21 per strip) instead of 49 ds_read_b32 per output.
// ---------------------------------------------------------------------------
__global__ __launch_bounds__(256) void dw7_kernel(
    const short* __restrict__ in, const float* __restrict__ dwk,
    float* __restrict__ out)
{
    int plane = blockIdx.x;
    int c = plane & (C_ - 1);
    const short* src = in + (size_t)plane * HW_;
    float* dst = out + (size_t)plane * HW_;
    __shared__ float tile[70 * 72];
    __shared__ float wk[49];
    int t = threadIdx.x;
    if (t < 49) wk[t] = dwk[c * 49 + t];
    for (int i = t; i < 70 * 72; i += 256) tile[i] = 0.f;
    __syncthreads();
    const short4v* src4 = (const short4v*)src;
    for (int i = t; i < HW_ / 4; i += 256) {
        short4v v = src4[i];
        int y = i >> 4, x = (i & 15) * 4;
        float* tp = &tile[(y + 3) * 72 + (x + 3)];
        tp[0] = bf2f(v.x); tp[1] = bf2f(v.y);
        tp[2] = bf2f(v.z); tp[3] = bf2f(v.w);
    }
    __syncthreads();
    #pragma unroll
    for (int it = 0; it < 4; ++it) {
        int idx = it * 256 + t;
        int y = idx >> 4;                 // 0..63
        int x0 = (idx & 15) * 4;          // 0..60
        float a0 = 0.f, a1 = 0.f, a2 = 0.f, a3 = 0.f;
        #pragma unroll
        for (int dy = 0; dy < 7; ++dy) {
            const float* tr = &tile[(y + dy) * 72 + x0];
            float4 ra = *(const float4*)tr;
            float4 rb = *(const float4*)(tr + 4);
            float4 rc = *(const float4*)(tr + 8);
            float r[12] = {ra.x, ra.y, ra.z, ra.w,
                           rb.x, rb.y, rb.z, rb.w,
                           rc.x, rc.y, rc.z, rc.w};
            const float* wr = &wk[dy * 7];
            #pragma unroll
            for (int dx = 0; dx < 7; ++dx) {
                float wv = wr[dx];
                a0 = fmaf(r[dx], wv, a0);
                a1 = fmaf(r[dx + 1], wv, a1);
                a2 = fmaf(r[dx + 2], wv, a2);
                a3 = fmaf(r[dx + 3], wv, a3);
            }
        }
        float4 o = {a0, a1, a2, a3};
        *(float4*)&dst[y * 64 + x0] = o;
    }
}

// ---------------------------------------------------------------------------
// K3: pointwise 256->18 conv + bias. One block per (b,row): 64 px, 4-way
// channel split, LDS partials + reduction. Grid = 256.
// ---------------------------------------------------------------------------
__global__ __launch_bounds__(256) void pw_off_kernel(
    const float* __restrict__ f, const float* __restrict__ pw,
    const float* __restrict__ pwb, float* __restrict__ off)
{
    int b = blockIdx.x >> 6;
    int rowblk = blockIdx.x & 63;
    __shared__ float wl[NOFF_ * C_];        // 18 KB
    __shared__ float part[4 * NOFF_ * 64];  // 18 KB
    int t = threadIdx.x;
    for (int i = t; i < NOFF_ * C_; i += 256) wl[i] = pw[i];
    __syncthreads();
    int px = t & 63, cs = t >> 6;
    int p = rowblk * 64 + px;
    const float* fb = f + (size_t)b * C_ * HW_ + (size_t)(cs * 64) * HW_ + p;
    float acc[NOFF_];
    #pragma unroll
    for (int o = 0; o < NOFF_; ++o) acc[o] = 0.f;
    for (int i = 0; i < 64; ++i) {
        float v = fb[(size_t)i * HW_];
        const float* wrow = &wl[cs * 64 + i];
        #pragma unroll
        for (int o = 0; o < NOFF_; ++o)
            acc[o] = fmaf(wrow[o * C_], v, acc[o]);
    }
    #pragma unroll
    for (int o = 0; o < NOFF_; ++o)
        part[(cs * NOFF_ + o) * 64 + px] = acc[o];
    __syncthreads();
    for (int idx = t; idx < NOFF_ * 64; idx += 256) {
        int o = idx >> 6, q = idx & 63;
        float sum = part[o * 64 + q] + part[(NOFF_ + o) * 64 + q]
                  + part[(2 * NOFF_ + o) * 64 + q] + part[(3 * NOFF_ + o) * 64 + q]
                  + pwb[o];
        off[((size_t)(b * NOFF_) + o) * HW_ + rowblk * 64 + q] = sum;
    }
}

// ---------------------------------------------------------------------------
// K4: pack w[o][c][3][3] (fp32) into fragment-major bf16.
// Fragment id = (slab, ot): slab = k*8+cc (72 slabs of K=32), ot = o/16.
// Lane holds A[o = ot*16+(lane&15)][c = cc*32+(lane>>4)*8+j], j contiguous.
// ---------------------------------------------------------------------------
__global__ __launch_bounds__(256) void wpack_kernel(
    const float* __restrict__ w, short* __restrict__ wp)
{
    int idx = blockIdx.x * 256 + threadIdx.x;   // 589824 total
    int j    = idx & 7;
    int lane = (idx >> 3) & 63;
    int ot   = (idx >> 9) & 15;
    int slab = idx >> 13;                        // 0..71
    int k = slab >> 3, cc = slab & 7;
    int o = ot * 16 + (lane & 15);
    int c = cc * 32 + (lane >> 4) * 8 + j;
    wp[idx] = f2bf(w[(size_t)(o * C_ + c) * KK_ + k]);
}

// ---------------------------------------------------------------------------
// K5: fused deformable gather + bf16-MFMA einsum + bias (+residual).
// 1024 threads (16 waves) per (b,row). h is pixel-major [HW][C] bf16, so a
// gather of 8 channels of one corner = one global_load_dwordx4 (8x fewer
// VMEM insts than scalar). K = 72 slabs of 32ch, staged 4 slabs/barrier.
// Staging thread: scb = t&3 (fastest!) so quarter-wave writes hit 16
// distinct 16B units -> 2-way bank aliasing = free. XOR swizzle
// (px+(px>>2))&3 keeps ds_read_b128 side ~2-way too.
// ---------------------------------------------------------------------------
__global__ __launch_bounds__(1024) void deform_mfma_kernel(
    const short* __restrict__ ht, const float* __restrict__ off,
    const short* __restrict__ wp, const float* __restrict__ bias,
    const float* __restrict__ resid, float* __restrict__ out)
{
    int b = blockIdx.x >> 6;
    int row = blockIdx.x & 63;
    __shared__ int   i00[576], i01[576], i10[576], i11[576];
    __shared__ float c00[576], c01[576], c10[576], c11[576];
    __shared__ __align__(16) short sbuf[2][8192];   // 2 x 16KB (4 slabs)
    int t = threadIdx.x;

    for (int e = t; e < 576; e += 1024) {
        int k = e >> 6, p = e & 63;
        float offy = off[((size_t)(b * NOFF_) + 2 * k) * HW_ + row * 64 + p];
        float offx = off[((size_t)(b * NOFF_) + 2 * k + 1) * HW_ + row * 64 + p];
        float py = (float)row + (float)(k / 3 - 1) + offy;
        float px = (float)p   + (float)(k % 3 - 1) + offx;
        float y0f = floorf(py), x0f = floorf(px);
        float wy1 = py - y0f, wx1 = px - x0f;
        float wy0 = 1.f - wy1, wx0 = 1.f - wx1;
        float y1f = y0f + 1.f, x1f = x0f + 1.f;
        bool vy0 = (y0f >= 0.f) && (y0f <= 63.f);
        bool vy1 = (y1f >= 0.f) && (y1f <= 63.f);
        bool vx0 = (x0f >= 0.f) && (x0f <= 63.f);
        bool vx1 = (x1f >= 0.f) && (x1f <= 63.f);
        int iy0 = (int)fminf(fmaxf(y0f, 0.f), 63.f);
        int iy1 = (int)fminf(fmaxf(y1f, 0.f), 63.f);
        int ix0 = (int)fminf(fmaxf(x0f, 0.f), 63.f);
        int ix1 = (int)fminf(fmaxf(x1f, 0.f), 63.f);
        i00[e] = iy0 * 64 + ix0; i01[e] = iy0 * 64 + ix1;
        i10[e] = iy1 * 64 + ix0; i11[e] = iy1 * 64 + ix1;
        c00[e] = (vy0 && vx0) ? wy0 * wx0 : 0.f;
        c01[e] = (vy0 && vx1) ? wy0 * wx1 : 0.f;
        c10[e] = (vy1 && vx0) ? wy1 * wx0 : 0.f;
        c11[e] = (vy1 && vx1) ? wy1 * wx1 : 0.f;
    }

    int wv = t >> 6;                 // wave id = o-tile (0..15)
    int lane = t & 63;
    int pq = lane >> 4, pr = lane & 15;

    // staging decomposition: ssl = slab-in-group, spx = pixel, scb = 8ch chunk
    int ssl = t >> 8;
    int su  = t & 255;
    int spx = su >> 2, scb = su & 3;
    const short* hb = ht + ((size_t)b * HW_) * C_;

    auto stage = [&](int g, int bi) {
        int s = 4 * g + ssl;
        int k = s >> 3, cc = s & 7;
        int e = k * 64 + spx;
        float w00 = c00[e], w01 = c01[e], w10 = c10[e], w11 = c11[e];
        const short* base = hb + cc * 32 + scb * 8;
        short8 A = *(const short8*)(base + (size_t)i00[e] * C_);
        short8 Bv = *(const short8*)(base + (size_t)i01[e] * C_);
        short8 Cv = *(const short8*)(base + (size_t)i10[e] * C_);
        short8 D = *(const short8*)(base + (size_t)i11[e] * C_);
        short8 v8;
        #pragma unroll
        for (int j = 0; j < 8; ++j) {
            float v = w00 * bf2f(A[j]) + w01 * bf2f(Bv[j])
                    + w10 * bf2f(Cv[j]) + w11 * bf2f(D[j]);
            v8[j] = f2bf(v);
        }
        int u2 = spx * 4 + (scb ^ ((spx + (spx >> 2)) & 3));
        *(short8*)&sbuf[bi][ssl * 2048 + u2 * 8] = v8;
    };

    floatx4 acc[4];
    #pragma unroll
    for (int pt = 0; pt < 4; ++pt) acc[pt] = (floatx4){0.f, 0.f, 0.f, 0.f};

    __syncthreads();                 // coeff tables ready
    stage(0, 0);
    __syncthreads();

    const short8* wp8 = (const short8*)wp;
    int ub[4];
    #pragma unroll
    for (int pt = 0; pt < 4; ++pt) {
        int px2 = pt * 16 + pr;
        ub[pt] = px2 * 4 + (pq ^ ((px2 + (px2 >> 2)) & 3));
    }

    for (int g = 0; g < 18; ++g) {
        short8 af[4];
        #pragma unroll
        for (int sl = 0; sl < 4; ++sl)
            af[sl] = wp8[(size_t)((4 * g + sl) * 16 + wv) * 64 + lane];
        if (g + 1 < 18) stage(g + 1, (g + 1) & 1);
        const short* sb = sbuf[g & 1];
        #pragma unroll
        for (int sl = 0; sl < 4; ++sl) {
            #pragma unroll
            for (int pt = 0; pt < 4; ++pt) {
                short8 bfv = *(const short8*)&sb[sl * 2048 + ub[pt] * 8];
                acc[pt] = __builtin_amdgcn_mfma_f32_16x16x32_bf16(
                    af[sl], bfv, acc[pt], 0, 0, 0);
            }
        }
        __syncthreads();
    }

    // epilogue: D layout col=lane&15 (pixel), row=(lane>>4)*4+reg (o-local)
    #pragma unroll
    for (int r = 0; r < 4; ++r) {
        int o = wv * 16 + pq * 4 + r;
        float bo = bias[o];
        size_t obase = ((size_t)(b * C_ + o)) * HW_ + row * 64 + pr;
        #pragma unroll
        for (int pt = 0; pt < 4; ++pt) {
            float v = acc[pt][r] + bo;
            if (resid) v += resid[obase + pt * 16];
            out[obase + pt * 16] = v;
        }
    }
}

// ---------------------------------------------------------------------------
extern "C" void kernel_launch(void* const* d_in, const int* in_sizes, int n_in,
                              void* d_out, int out_size, void* d_ws, size_t ws_size,
                              hipStream_t stream)
{
    const float* x     = (const float*)d_in[0];
    const float* gn1_g = (const float*)d_in[1];
    const float* gn1_b = (const float*)d_in[2];
    const float* dw1   = (const float*)d_in[3];
    const float* pw1   = (const float*)d_in[4];
    const float* pwb1  = (const float*)d_in[5];
    const float* w1    = (const float*)d_in[6];
    const float* b1    = (const float*)d_in[7];
    const float* gn2_g = (const float*)d_in[8];
    const float* gn2_b = (const float*)d_in[9];
    const float* dw2   = (const float*)d_in[10];
    const float* pw2   = (const float*)d_in[11];
    const float* pwb2  = (const float*)d_in[12];
    const float* w2    = (const float*)d_in[13];
    const float* b2    = (const float*)d_in[14];
    float* out = (float*)d_out;

    float* ws   = (float*)d_ws;
    float* fy   = ws;                          // 4,194,304 floats (16 MB)
    short* hbf  = (short*)(ws + 4194304);      // [C][HW] bf16 (8 MB)
    short* hbt  = (short*)(ws + 6291456);      // [HW][C] bf16 (8 MB)
    float* offb = ws + 8388608;                // 294,912
    short* wp1  = (short*)(ws + 8683520);      // 589,824 bf16
    short* wp2  = (short*)(ws + 8978432);      // 589,824 bf16

    wpack_kernel<<<2304, 256, 0, stream>>>(w1, wp1);
    wpack_kernel<<<2304, 256, 0, stream>>>(w2, wp2);

    // layer 1
    gn_relu_kernel<<<B_ * NG_, 256, 0, stream>>>(x, gn1_g, gn1_b, hbf);
    transpose_kernel<<<2048, 256, 0, stream>>>(hbf, hbt);
    dw7_kernel<<<B_ * C_, 256, 0, stream>>>(hbf, dw1, fy);
    pw_off_kernel<<<B_ * H_, 256, 0, stream>>>(fy, pw1, pwb1, offb);
    deform_mfma_kernel<<<B_ * H_, 1024, 0, stream>>>(hbt, offb, wp1, b1, nullptr, fy);

    // layer 2 (+ residual x)
    gn_relu_kernel<<<B_ * NG_, 256, 0, stream>>>(fy, gn2_g, gn2_b, hbf);
    transpose_kernel<<<2048, 256, 0, stream>>>(hbf, hbt);
    dw7_kernel<<<B_ * C_, 256, 0, stream>>>(hbf, dw2, fy);
    pw_off_kernel<<<B_ * H_, 256, 0, stream>>>(fy, pw2, pwb2, offb);
    deform_mfma_kernel<<<B_ * H_, 1024, 0, stream>>>(hbt, offb, wp2, b2, x, out);
}

// Round 5
// 291.670 us; speedup vs baseline: 4.3256x; 1.1756x over previous
//
#include <hip/hip_runtime.h>

#define B_    4
#define C_    256
#define H_    64
#define W_    64
#define HW_   4096
#define NG_   32
#define CPG_  8
#define KK_   9
#define NOFF_ 18

typedef __attribute__((ext_vector_type(8))) short short8;
typedef __attribute__((ext_vector_type(4))) short short4v;
typedef __attribute__((ext_vector_type(4))) float floatx4;

static __device__ __forceinline__ short f2bf(float f) {
    union { float f; unsigned u; } v; v.f = f;
    unsigned r = v.u + 0x7fff + ((v.u >> 16) & 1);   // RNE
    return (short)(r >> 16);
}
static __device__ __forceinline__ float bf2f(short s) {
    union { unsigned u; float f; } v;
    v.u = ((unsigned)(unsigned short)s) << 16;
    return v.f;
}

// ---------------------------------------------------------------------------
// K1: GroupNorm (32 groups) + ReLU, fp32 [C][HW] in -> bf16 [C][HW] out.
// One block (1024 thr, 16 waves) per (b, group) for latency hiding.
// ---------------------------------------------------------------------------
__global__ __launch_bounds__(1024) void gn_relu_kernel(
    const float* __restrict__ in, const float* __restrict__ gamma,
    const float* __restrict__ beta, short* __restrict__ outb)
{
    int b = blockIdx.x >> 5;
    int g = blockIdx.x & 31;
    const int N = CPG_ * HW_;              // 32768
    size_t base = ((size_t)(b * C_ + g * CPG_)) * HW_;
    const float4* in4 = (const float4*)(in + base);
    int t = threadIdx.x;

    float s = 0.f, ss = 0.f;
    for (int i = t; i < N / 4; i += 1024) {
        float4 v = in4[i];
        s  += v.x + v.y + v.z + v.w;
        ss += v.x * v.x + v.y * v.y + v.z * v.z + v.w * v.w;
    }
    #pragma unroll
    for (int off = 32; off > 0; off >>= 1) {
        s  += __shfl_down(s, off, 64);
        ss += __shfl_down(ss, off, 64);
    }
    __shared__ float red[32];
    __shared__ float sh_rs, sh_m;
    int wid = t >> 6;
    if ((t & 63) == 0) { red[wid] = s; red[16 + wid] = ss; }
    __syncthreads();
    if (t == 0) {
        float S = 0.f, SS = 0.f;
        #pragma unroll
        for (int i = 0; i < 16; ++i) { S += red[i]; SS += red[16 + i]; }
        float m = S / (float)N;
        float var = SS / (float)N - m * m;
        sh_rs = rsqrtf(var + 1e-5f);
        sh_m = m;
    }
    __syncthreads();
    float rs = sh_rs, m = sh_m;
    short4v* out4 = (short4v*)(outb + base);
    for (int i = t; i < N / 4; i += 1024) {
        int ch = g * CPG_ + (i >> 10);
        float ga = gamma[ch] * rs;
        float be = beta[ch] - m * ga;
        float4 v = in4[i];
        short4v o;
        o.x = f2bf(fmaxf(fmaf(v.x, ga, be), 0.f));
        o.y = f2bf(fmaxf(fmaf(v.y, ga, be), 0.f));
        o.z = f2bf(fmaxf(fmaf(v.z, ga, be), 0.f));
        o.w = f2bf(fmaxf(fmaf(v.w, ga, be), 0.f));
        out4[i] = o;
    }
}

// ---------------------------------------------------------------------------
// K2: depthwise 7x7 SAME conv + transpose emit. bf16 [C][HW] in.
// Outputs: fdw bf16 [HW][C] (conv result, for fused pw) and hbt bf16
// [HW][C] (transposed input, for the deform gather). One block per (b,c).
// ---------------------------------------------------------------------------
__global__ __launch_bounds__(256) void dw7t_kernel(
    const short* __restrict__ in, const float* __restrict__ dwk,
    short* __restrict__ fdw, short* __restrict__ hbt)
{
    int plane = blockIdx.x;
    int b = plane >> 8;
    int c = plane & (C_ - 1);
    const short* src = in + (size_t)plane * HW_;
    __shared__ float tile[70 * 72];
    __shared__ float wk[49];
    int t = threadIdx.x;
    if (t < 49) wk[t] = dwk[c * 49 + t];
    for (int i = t; i < 70 * 72; i += 256) tile[i] = 0.f;
    __syncthreads();
    const short4v* src4 = (const short4v*)src;
    short* hb = hbt + ((size_t)b * HW_) * C_ + c;
    for (int i = t; i < HW_ / 4; i += 256) {
        short4v v = src4[i];
        int y = i >> 4, x = (i & 15) * 4;
        float* tp = &tile[(y + 3) * 72 + (x + 3)];
        tp[0] = bf2f(v.x); tp[1] = bf2f(v.y);
        tp[2] = bf2f(v.z); tp[3] = bf2f(v.w);
        int px = i * 4;
        hb[(size_t)px * C_]       = v.x;
        hb[(size_t)(px + 1) * C_] = v.y;
        hb[(size_t)(px + 2) * C_] = v.z;
        hb[(size_t)(px + 3) * C_] = v.w;
    }
    __syncthreads();
    short* fb = fdw + ((size_t)b * HW_) * C_ + c;
    #pragma unroll
    for (int it = 0; it < 4; ++it) {
        int idx = it * 256 + t;
        int y = idx >> 4;                 // 0..63
        int x0 = (idx & 15) * 4;          // 0..60
        float a0 = 0.f, a1 = 0.f, a2 = 0.f, a3 = 0.f;
        #pragma unroll
        for (int dy = 0; dy < 7; ++dy) {
            const float* tr = &tile[(y + dy) * 72 + x0];
            float4 ra = *(const float4*)tr;
            float4 rb = *(const float4*)(tr + 4);
            float4 rc = *(const float4*)(tr + 8);
            float r[12] = {ra.x, ra.y, ra.z, ra.w,
                           rb.x, rb.y, rb.z, rb.w,
                           rc.x, rc.y, rc.z, rc.w};
            const float* wr = &wk[dy * 7];
            #pragma unroll
            for (int dx = 0; dx < 7; ++dx) {
                float wv = wr[dx];
                a0 = fmaf(r[dx], wv, a0);
                a1 = fmaf(r[dx + 1], wv, a1);
                a2 = fmaf(r[dx + 2], wv, a2);
                a3 = fmaf(r[dx + 3], wv, a3);
            }
        }
        size_t ob = (size_t)(y * 64 + x0) * C_;
        fb[ob]          = f2bf(a0);
        fb[ob + C_]     = f2bf(a1);
        fb[ob + 2 * C_] = f2bf(a2);
        fb[ob + 3 * C_] = f2bf(a3);
    }
}

// ---------------------------------------------------------------------------
// K3: pack all weights (one launch). Blocks 0..4607: main conv w1/w2
// [O][C][3][3] fp32 -> fragment-major bf16 (slab = k*8+cc, ot = o/16; lane
// holds A[ot*16+(lane&15)][cc*32+(lane>>4)*8+j]). Blocks 4608..4671:
// offset-predictor pw1/pw2 [18][C] -> A-frags padded to 32 rows
// (sl = k/32 slab, ot in {0,1}).
// ---------------------------------------------------------------------------
__global__ __launch_bounds__(256) void wpack_all_kernel(
    const float* __restrict__ w1, const float* __restrict__ w2,
    const float* __restrict__ pw1, const float* __restrict__ pw2,
    short* __restrict__ wp1, short* __restrict__ wp2,
    short* __restrict__ ppk1, short* __restrict__ ppk2)
{
    int blk = blockIdx.x;
    if (blk < 4608) {
        const float* w = (blk < 2304) ? w1 : w2;
        short* wp = (blk < 2304) ? wp1 : wp2;
        int idx = (blk & 2047) * 256 + ((blk & 2048) ? 524288 : 0) + threadIdx.x;
        // simpler: recompute from (blk % 2304)
        idx = (blk % 2304) * 256 + threadIdx.x;
        int j    = idx & 7;
        int lane = (idx >> 3) & 63;
        int ot   = (idx >> 9) & 15;
        int slab = idx >> 13;                        // 0..71
        int k = slab >> 3, cc = slab & 7;
        int o = ot * 16 + (lane & 15);
        int c = cc * 32 + (lane >> 4) * 8 + j;
        wp[idx] = f2bf(w[(size_t)(o * C_ + c) * KK_ + k]);
    } else {
        int q = blk - 4608;                          // 0..63
        const float* pw = (q < 32) ? pw1 : pw2;
        short* ppk = (q < 32) ? ppk1 : ppk2;
        int idx = (q & 31) * 256 + threadIdx.x;      // 0..8191
        int j = idx & 7, lane = (idx >> 3) & 63;
        int ot = (idx >> 9) & 1, sl = idx >> 10;     // 0..7
        int o = ot * 16 + (lane & 15);
        int k = sl * 32 + (lane >> 4) * 8 + j;
        ppk[idx] = (o < NOFF_) ? f2bf(pw[o * C_ + k]) : (short)0;
    }
}

// ---------------------------------------------------------------------------
// K4: fused {pw offsets + bilinear setup + deformable gather + MFMA einsum
// + bias (+residual)}. One block (1024 thr, 16 waves) per (b,row).
//   Stage A: offsets via MFMA — A = packed pw frags, B = fdw[px][c] read
//            directly from global as B-frags (pixel-major makes the frag a
//            single b128 per lane). Result + pwb -> off_lds.
//   Stage B: bilinear corner idx/weights (OOB folded into zero weights).
//   Stage C: K = 9 taps x 256 ch; group g = tap g (8 slabs of 32ch, 32KB).
//            Software pipeline: corner loads for g+2 issued before the
//            barrier; staging VALU for g+1 runs after MFMA of g.
// ---------------------------------------------------------------------------
__global__ __launch_bounds__(1024) void deform_fused_kernel(
    const short* __restrict__ ht,   const short* __restrict__ fdw,
    const short* __restrict__ ppk,  const float* __restrict__ pwb,
    const short* __restrict__ wp,   const float* __restrict__ bias,
    const float* __restrict__ resid, float* __restrict__ out)
{
    int b = blockIdx.x >> 6;
    int row = blockIdx.x & 63;
    __shared__ int   i00[576], i01[576], i10[576], i11[576];
    __shared__ float c00[576], c01[576], c10[576], c11[576];
    __shared__ float off_lds[NOFF_ * 64];
    __shared__ __align__(16) short sbuf[2][16384];   // 2 x 32KB (8 slabs)
    int t = threadIdx.x;
    int wv = t >> 6, lane = t & 63;
    int pq = lane >> 4, pr = lane & 15;

    // ---- stage A: pw offsets via MFMA (waves 0..7) ----
    if (wv < 8) {
        int ot = wv & 1, ptw = wv >> 1;
        int px = ptw * 16 + pr;
        const short8* fb8 = (const short8*)(fdw +
            ((size_t)b * HW_ + row * 64 + px) * C_);
        const short8* ap = (const short8*)ppk;
        floatx4 pacc = (floatx4){0.f, 0.f, 0.f, 0.f};
        #pragma unroll
        for (int sl = 0; sl < 8; ++sl) {
            short8 af = ap[(sl * 2 + ot) * 64 + lane];
            short8 bf = fb8[sl * 4 + pq];
            pacc = __builtin_amdgcn_mfma_f32_16x16x32_bf16(af, bf, pacc, 0, 0, 0);
        }
        #pragma unroll
        for (int r = 0; r < 4; ++r) {
            int o = ot * 16 + pq * 4 + r;
            if (o < NOFF_) off_lds[o * 64 + px] = pacc[r] + pwb[o];
        }
    }
    __syncthreads();

    // ---- stage B: bilinear coefficient tables ----
    if (t < 576) {
        int e = t;
        int k = e >> 6, p = e & 63;
        float offy = off_lds[(2 * k) * 64 + p];
        float offx = off_lds[(2 * k + 1) * 64 + p];
        float py = (float)row + (float)(k / 3 - 1) + offy;
        float px = (float)p   + (float)(k % 3 - 1) + offx;
        float y0f = floorf(py), x0f = floorf(px);
        float wy1 = py - y0f, wx1 = px - x0f;
        float wy0 = 1.f - wy1, wx0 = 1.f - wx1;
        float y1f = y0f + 1.f, x1f = x0f + 1.f;
        bool vy0 = (y0f >= 0.f) && (y0f <= 63.f);
        bool vy1 = (y1f >= 0.f) && (y1f <= 63.f);
        bool vx0 = (x0f >= 0.f) && (x0f <= 63.f);
        bool vx1 = (x1f >= 0.f) && (x1f <= 63.f);
        int iy0 = (int)fminf(fmaxf(y0f, 0.f), 63.f);
        int iy1 = (int)fminf(fmaxf(y1f, 0.f), 63.f);
        int ix0 = (int)fminf(fmaxf(x0f, 0.f), 63.f);
        int ix1 = (int)fminf(fmaxf(x1f, 0.f), 63.f);
        i00[e] = iy0 * 64 + ix0; i01[e] = iy0 * 64 + ix1;
        i10[e] = iy1 * 64 + ix0; i11[e] = iy1 * 64 + ix1;
        c00[e] = (vy0 && vx0) ? wy0 * wx0 : 0.f;
        c01[e] = (vy0 && vx1) ? wy0 * wx1 : 0.f;
        c10[e] = (vy1 && vx0) ? wy1 * wx0 : 0.f;
        c11[e] = (vy1 && vx1) ? wy1 * wx1 : 0.f;
    }
    __syncthreads();

    // ---- stage C ----
    // staging unit decomposition: cb = t&3 (fastest), px = (t>>2)&63,
    // slabs ssl0 and ssl0+4 per thread.
    int scb = t & 3, spx = (t >> 2) & 63, ssl0 = t >> 8;
    int u2 = spx * 4 + (scb ^ ((spx + (spx >> 2)) & 3));
    const short* hb = ht + ((size_t)b * HW_) * C_;
    const short* hb0 = hb + ssl0 * 32 + scb * 8;
    const short* hb1 = hb + (ssl0 + 4) * 32 + scb * 8;

    short8 ra[4], rb[4];          // prefetched corners, 2 units
    auto prefetch = [&](int g) {
        int e = g * 64 + spx;
        int a00 = i00[e], a01 = i01[e], a10 = i10[e], a11 = i11[e];
        ra[0] = *(const short8*)(hb0 + (size_t)a00 * C_);
        ra[1] = *(const short8*)(hb0 + (size_t)a01 * C_);
        ra[2] = *(const short8*)(hb0 + (size_t)a10 * C_);
        ra[3] = *(const short8*)(hb0 + (size_t)a11 * C_);
        rb[0] = *(const short8*)(hb1 + (size_t)a00 * C_);
        rb[1] = *(const short8*)(hb1 + (size_t)a01 * C_);
        rb[2] = *(const short8*)(hb1 + (size_t)a10 * C_);
        rb[3] = *(const short8*)(hb1 + (size_t)a11 * C_);
    };
    auto stage_write = [&](int g, int bi) {
        int e = g * 64 + spx;
        float w00 = c00[e], w01 = c01[e], w10 = c10[e], w11 = c11[e];
        short8 va, vb;
        #pragma unroll
        for (int j = 0; j < 8; ++j) {
            va[j] = f2bf(w00 * bf2f(ra[0][j]) + w01 * bf2f(ra[1][j])
                       + w10 * bf2f(ra[2][j]) + w11 * bf2f(ra[3][j]));
            vb[j] = f2bf(w00 * bf2f(rb[0][j]) + w01 * bf2f(rb[1][j])
                       + w10 * bf2f(rb[2][j]) + w11 * bf2f(rb[3][j]));
        }
        *(short8*)&sbuf[bi][ssl0 * 2048 + u2 * 8] = va;
        *(short8*)&sbuf[bi][(ssl0 + 4) * 2048 + u2 * 8] = vb;
    };

    floatx4 acc[4];
    #pragma unroll
    for (int pt = 0; pt < 4; ++pt) acc[pt] = (floatx4){0.f, 0.f, 0.f, 0.f};
    int ub[4];
    #pragma unroll
    for (int pt = 0; pt < 4; ++pt) {
        int px2 = pt * 16 + pr;
        ub[pt] = px2 * 4 + (pq ^ ((px2 + (px2 >> 2)) & 3));
    }

    prefetch(0);
    stage_write(0, 0);
    prefetch(1);
    __syncthreads();

    const short8* wp8 = (const short8*)wp;
    for (int g = 0; g < 9; ++g) {
        const short* sb = sbuf[g & 1];
        #pragma unroll
        for (int half = 0; half < 2; ++half) {
            short8 af[4];
            #pragma unroll
            for (int q = 0; q < 4; ++q)
                af[q] = wp8[(size_t)((g * 8 + half * 4 + q) * 16 + wv) * 64 + lane];
            #pragma unroll
            for (int q = 0; q < 4; ++q) {
                int sl = half * 4 + q;
                #pragma unroll
                for (int pt = 0; pt < 4; ++pt) {
                    short8 bfv = *(const short8*)&sb[sl * 2048 + ub[pt] * 8];
                    acc[pt] = __builtin_amdgcn_mfma_f32_16x16x32_bf16(
                        af[q], bfv, acc[pt], 0, 0, 0);
                }
            }
        }
        if (g + 1 < 9) {
            stage_write(g + 1, (g + 1) & 1);
            if (g + 2 < 9) prefetch(g + 2);
        }
        __syncthreads();
    }

    // ---- epilogue: D layout col=lane&15 (pixel), row=(lane>>4)*4+reg ----
    #pragma unroll
    for (int r = 0; r < 4; ++r) {
        int o = wv * 16 + pq * 4 + r;
        float bo = bias[o];
        size_t obase = ((size_t)(b * C_ + o)) * HW_ + row * 64 + pr;
        #pragma unroll
        for (int pt = 0; pt < 4; ++pt) {
            float v = acc[pt][r] + bo;
            if (resid) v += resid[obase + pt * 16];
            out[obase + pt * 16] = v;
        }
    }
}

// ---------------------------------------------------------------------------
extern "C" void kernel_launch(void* const* d_in, const int* in_sizes, int n_in,
                              void* d_out, int out_size, void* d_ws, size_t ws_size,
                              hipStream_t stream)
{
    const float* x     = (const float*)d_in[0];
    const float* gn1_g = (const float*)d_in[1];
    const float* gn1_b = (const float*)d_in[2];
    const float* dw1   = (const float*)d_in[3];
    const float* pw1   = (const float*)d_in[4];
    const float* pwb1  = (const float*)d_in[5];
    const float* w1    = (const float*)d_in[6];
    const float* b1    = (const float*)d_in[7];
    const float* gn2_g = (const float*)d_in[8];
    const float* gn2_b = (const float*)d_in[9];
    const float* dw2   = (const float*)d_in[10];
    const float* pw2   = (const float*)d_in[11];
    const float* pwb2  = (const float*)d_in[12];
    const float* w2    = (const float*)d_in[13];
    const float* b2    = (const float*)d_in[14];
    float* out = (float*)d_out;

    float* ws   = (float*)d_ws;
    float* y1   = ws;                          // fp32 [B][C][HW]  (16 MB)
    short* hbf  = (short*)(ws + 4194304);      // bf16 [B][C][HW]  (8 MB)
    short* hbt  = (short*)(ws + 6291456);      // bf16 [B][HW][C]  (8 MB)
    short* fdw  = (short*)(ws + 8388608);      // bf16 [B][HW][C]  (8 MB)
    short* wp1  = (short*)(ws + 10485760);     // 589,824 bf16
    short* wp2  = (short*)(ws + 10780672);     // 589,824 bf16
    short* ppk1 = (short*)(ws + 11075584);     // 8,192 bf16
    short* ppk2 = (short*)(ws + 11079680);     // 8,192 bf16

    wpack_all_kernel<<<4672, 256, 0, stream>>>(w1, w2, pw1, pw2,
                                               wp1, wp2, ppk1, ppk2);

    // layer 1
    gn_relu_kernel<<<B_ * NG_, 1024, 0, stream>>>(x, gn1_g, gn1_b, hbf);
    dw7t_kernel<<<B_ * C_, 256, 0, stream>>>(hbf, dw1, fdw, hbt);
    deform_fused_kernel<<<B_ * H_, 1024, 0, stream>>>(
        hbt, fdw, ppk1, pwb1, wp1, b1, nullptr, y1);

    // layer 2 (+ residual x)
    gn_relu_kernel<<<B_ * NG_, 1024, 0, stream>>>(y1, gn2_g, gn2_b, hbf);
    dw7t_kernel<<<B_ * C_, 256, 0, stream>>>(hbf, dw2, fdw, hbt);
    deform_fused_kernel<<<B_ * H_, 1024, 0, stream>>>(
        hbt, fdw, ppk2, pwb2, wp2, b2, x, out);
}

// Round 6
// 250.454 us; speedup vs baseline: 5.0374x; 1.1646x over previous
//
#include <hip/hip_runtime.h>

#define B_    4
#define C_    256
#define H_    64
#define W_    64
#define HW_   4096
#define NG_   32
#define CPG_  8
#define KK_   9
#define NOFF_ 18

typedef __attribute__((ext_vector_type(8))) short short8;
typedef __attribute__((ext_vector_type(4))) short short4v;
typedef __attribute__((ext_vector_type(4))) float floatx4;

static __device__ __forceinline__ short f2bf(float f) {
    union { float f; unsigned u; } v; v.f = f;
    unsigned r = v.u + 0x7fff + ((v.u >> 16) & 1);   // RNE
    return (short)(r >> 16);
}
static __device__ __forceinline__ float bf2f(short s) {
    union { unsigned u; float f; } v;
    v.u = ((unsigned)(unsigned short)s) << 16;
    return v.f;
}

// ---------------------------------------------------------------------------
// K1: GroupNorm (32 groups) + ReLU -> bf16 [C][HW]. fp32-input variant.
// One block (1024 thr) per (b, group).
// ---------------------------------------------------------------------------
__global__ __launch_bounds__(1024) void gn_relu_f32_kernel(
    const float* __restrict__ in, const float* __restrict__ gamma,
    const float* __restrict__ beta, short* __restrict__ outb)
{
    int b = blockIdx.x >> 5;
    int g = blockIdx.x & 31;
    const int N = CPG_ * HW_;              // 32768
    size_t base = ((size_t)(b * C_ + g * CPG_)) * HW_;
    const float4* in4 = (const float4*)(in + base);
    int t = threadIdx.x;

    float s = 0.f, ss = 0.f;
    for (int i = t; i < N / 4; i += 1024) {
        float4 v = in4[i];
        s  += v.x + v.y + v.z + v.w;
        ss += v.x * v.x + v.y * v.y + v.z * v.z + v.w * v.w;
    }
    #pragma unroll
    for (int off = 32; off > 0; off >>= 1) {
        s  += __shfl_down(s, off, 64);
        ss += __shfl_down(ss, off, 64);
    }
    __shared__ float red[32];
    __shared__ float sh_rs, sh_m;
    int wid = t >> 6;
    if ((t & 63) == 0) { red[wid] = s; red[16 + wid] = ss; }
    __syncthreads();
    if (t == 0) {
        float S = 0.f, SS = 0.f;
        #pragma unroll
        for (int i = 0; i < 16; ++i) { S += red[i]; SS += red[16 + i]; }
        float m = S / (float)N;
        float var = SS / (float)N - m * m;
        sh_rs = rsqrtf(var + 1e-5f);
        sh_m = m;
    }
    __syncthreads();
    float rs = sh_rs, m = sh_m;
    short4v* out4 = (short4v*)(outb + base);
    for (int i = t; i < N / 4; i += 1024) {
        int ch = g * CPG_ + (i >> 10);
        float ga = gamma[ch] * rs;
        float be = beta[ch] - m * ga;
        float4 v = in4[i];
        short4v o;
        o.x = f2bf(fmaxf(fmaf(v.x, ga, be), 0.f));
        o.y = f2bf(fmaxf(fmaf(v.y, ga, be), 0.f));
        o.z = f2bf(fmaxf(fmaf(v.z, ga, be), 0.f));
        o.w = f2bf(fmaxf(fmaf(v.w, ga, be), 0.f));
        out4[i] = o;
    }
}

// bf16-input variant (reads layer-1 output y1 in bf16)
__global__ __launch_bounds__(1024) void gn_relu_bf16_kernel(
    const short* __restrict__ in, const float* __restrict__ gamma,
    const float* __restrict__ beta, short* __restrict__ outb)
{
    int b = blockIdx.x >> 5;
    int g = blockIdx.x & 31;
    const int N = CPG_ * HW_;
    size_t base = ((size_t)(b * C_ + g * CPG_)) * HW_;
    const short4v* in4 = (const short4v*)(in + base);
    int t = threadIdx.x;

    float s = 0.f, ss = 0.f;
    for (int i = t; i < N / 4; i += 1024) {
        short4v sv = in4[i];
        float vx = bf2f(sv.x), vy = bf2f(sv.y), vz = bf2f(sv.z), vw = bf2f(sv.w);
        s  += vx + vy + vz + vw;
        ss += vx * vx + vy * vy + vz * vz + vw * vw;
    }
    #pragma unroll
    for (int off = 32; off > 0; off >>= 1) {
        s  += __shfl_down(s, off, 64);
        ss += __shfl_down(ss, off, 64);
    }
    __shared__ float red[32];
    __shared__ float sh_rs, sh_m;
    int wid = t >> 6;
    if ((t & 63) == 0) { red[wid] = s; red[16 + wid] = ss; }
    __syncthreads();
    if (t == 0) {
        float S = 0.f, SS = 0.f;
        #pragma unroll
        for (int i = 0; i < 16; ++i) { S += red[i]; SS += red[16 + i]; }
        float m = S / (float)N;
        float var = SS / (float)N - m * m;
        sh_rs = rsqrtf(var + 1e-5f);
        sh_m = m;
    }
    __syncthreads();
    float rs = sh_rs, m = sh_m;
    short4v* out4 = (short4v*)(outb + base);
    for (int i = t; i < N / 4; i += 1024) {
        int ch = g * CPG_ + (i >> 10);
        float ga = gamma[ch] * rs;
        float be = beta[ch] - m * ga;
        short4v sv = in4[i];
        short4v o;
        o.x = f2bf(fmaxf(fmaf(bf2f(sv.x), ga, be), 0.f));
        o.y = f2bf(fmaxf(fmaf(bf2f(sv.y), ga, be), 0.f));
        o.z = f2bf(fmaxf(fmaf(bf2f(sv.z), ga, be), 0.f));
        o.w = f2bf(fmaxf(fmaf(bf2f(sv.w), ga, be), 0.f));
        out4[i] = o;
    }
}

// ---------------------------------------------------------------------------
// K2: depthwise 7x7 SAME conv, bf16 [C][HW] in -> bf16 [C][HW] out
// (coalesced short4 stores). One block per (b,c) plane.
// ---------------------------------------------------------------------------
__global__ __launch_bounds__(256) void dw7_kernel(
    const short* __restrict__ in, const float* __restrict__ dwk,
    short* __restrict__ out)
{
    int plane = blockIdx.x;
    int c = plane & (C_ - 1);
    const short* src = in + (size_t)plane * HW_;
    short* dst = out + (size_t)plane * HW_;
    __shared__ float tile[70 * 72];
    __shared__ float wk[49];
    int t = threadIdx.x;
    if (t < 49) wk[t] = dwk[c * 49 + t];
    for (int i = t; i < 70 * 72; i += 256) tile[i] = 0.f;
    __syncthreads();
    const short4v* src4 = (const short4v*)src;
    for (int i = t; i < HW_ / 4; i += 256) {
        short4v v = src4[i];
        int y = i >> 4, x = (i & 15) * 4;
        float* tp = &tile[(y + 3) * 72 + (x + 3)];
        tp[0] = bf2f(v.x); tp[1] = bf2f(v.y);
        tp[2] = bf2f(v.z); tp[3] = bf2f(v.w);
    }
    __syncthreads();
    #pragma unroll
    for (int it = 0; it < 4; ++it) {
        int idx = it * 256 + t;
        int y = idx >> 4;                 // 0..63
        int x0 = (idx & 15) * 4;          // 0..60
        float a0 = 0.f, a1 = 0.f, a2 = 0.f, a3 = 0.f;
        #pragma unroll
        for (int dy = 0; dy < 7; ++dy) {
            const float* tr = &tile[(y + dy) * 72 + x0];
            float4 ra = *(const float4*)tr;
            float4 rb = *(const float4*)(tr + 4);
            float4 rc = *(const float4*)(tr + 8);
            float r[12] = {ra.x, ra.y, ra.z, ra.w,
                           rb.x, rb.y, rb.z, rb.w,
                           rc.x, rc.y, rc.z, rc.w};
            const float* wr = &wk[dy * 7];
            #pragma unroll
            for (int dx = 0; dx < 7; ++dx) {
                float wv = wr[dx];
                a0 = fmaf(r[dx], wv, a0);
                a1 = fmaf(r[dx + 1], wv, a1);
                a2 = fmaf(r[dx + 2], wv, a2);
                a3 = fmaf(r[dx + 3], wv, a3);
            }
        }
        short4v o;
        o.x = f2bf(a0); o.y = f2bf(a1); o.z = f2bf(a2); o.w = f2bf(a3);
        *(short4v*)&dst[y * 64 + x0] = o;
    }
}

// ---------------------------------------------------------------------------
// K2b: LDS-tiled transpose bf16 [C][HW] -> [HW][C], both tensors in one
// launch (blk<256: A, else B). Tile = 64 px x 256 ch. Channel PAIRS packed
// into 32-bit words; XOR swizzle on word-column bits>=2 keeps uint4 reads
// 16B-aligned and banks spread. Reads: 128B row segments. Writes: 512B
// contiguous per 32 lanes. Fully coalesced both sides.
// ---------------------------------------------------------------------------
__global__ __launch_bounds__(256) void transpose2_kernel(
    const short* __restrict__ srcA, short* __restrict__ dstA,
    const short* __restrict__ srcB, short* __restrict__ dstB)
{
    int blk = blockIdx.x;                  // 0..511
    const short* src = (blk < 256) ? srcA : srcB;
    short*       dst = (blk < 256) ? dstA : dstB;
    int q = blk & 255;
    int b = q >> 6;
    int px0 = (q & 63) * 64;
    __shared__ unsigned ltile[64 * 132];   // 33 KB
    int t = threadIdx.x;
    const short* sb = src + (size_t)b * C_ * HW_;

    int pq4 = t & 15, cphi = t >> 4;
    #pragma unroll
    for (int i = 0; i < 8; ++i) {
        int cp = i * 16 + cphi;            // channel pair 0..127
        const short* r0 = sb + (size_t)(2 * cp) * HW_ + px0 + pq4 * 4;
        short4v lo = *(const short4v*)r0;
        short4v hi = *(const short4v*)(r0 + HW_);
        #pragma unroll
        for (int j = 0; j < 4; ++j) {
            int pl = pq4 * 4 + j;
            unsigned wrd = (unsigned)(unsigned short)lo[j]
                         | ((unsigned)(unsigned short)hi[j] << 16);
            ltile[pl * 132 + (cp ^ ((pl & 7) << 2))] = wrd;
        }
    }
    __syncthreads();

    int co = t & 31, ph = t >> 5;
    #pragma unroll
    for (int r = 0; r < 8; ++r) {
        int pl = r * 8 + ph;
        uint4 v = *(const uint4*)&ltile[pl * 132 + ((co * 4) ^ ((pl & 7) << 2))];
        *(uint4*)(dst + ((size_t)b * HW_ + px0 + pl) * C_ + co * 8) = v;
    }
}

// ---------------------------------------------------------------------------
// K3: pack all weights (one launch). Blocks 0..4607: w1/w2 -> fragment-major
// bf16. Blocks 4608..4671: pw1/pw2 -> A-frags padded to 32 rows.
// ---------------------------------------------------------------------------
__global__ __launch_bounds__(256) void wpack_all_kernel(
    const float* __restrict__ w1, const float* __restrict__ w2,
    const float* __restrict__ pw1, const float* __restrict__ pw2,
    short* __restrict__ wp1, short* __restrict__ wp2,
    short* __restrict__ ppk1, short* __restrict__ ppk2)
{
    int blk = blockIdx.x;
    if (blk < 4608) {
        const float* w = (blk < 2304) ? w1 : w2;
        short* wp = (blk < 2304) ? wp1 : wp2;
        int idx = (blk % 2304) * 256 + threadIdx.x;
        int j    = idx & 7;
        int lane = (idx >> 3) & 63;
        int ot   = (idx >> 9) & 15;
        int slab = idx >> 13;                        // 0..71
        int k = slab >> 3, cc = slab & 7;
        int o = ot * 16 + (lane & 15);
        int c = cc * 32 + (lane >> 4) * 8 + j;
        wp[idx] = f2bf(w[(size_t)(o * C_ + c) * KK_ + k]);
    } else {
        int q = blk - 4608;                          // 0..63
        const float* pw = (q < 32) ? pw1 : pw2;
        short* ppk = (q < 32) ? ppk1 : ppk2;
        int idx = (q & 31) * 256 + threadIdx.x;      // 0..8191
        int j = idx & 7, lane = (idx >> 3) & 63;
        int ot = (idx >> 9) & 1, sl = idx >> 10;     // 0..7
        int o = ot * 16 + (lane & 15);
        int k = sl * 32 + (lane >> 4) * 8 + j;
        ppk[idx] = (o < NOFF_) ? f2bf(pw[o * C_ + k]) : (short)0;
    }
}

// ---------------------------------------------------------------------------
// K4: fused {pw offsets (MFMA) + bilinear setup + deformable gather + MFMA
// einsum + bias (+residual)}. One block (1024 thr) per (b,row). Output is
// bf16 (outb) for layer 1, fp32+resid (outf) for layer 2.
// ---------------------------------------------------------------------------
__global__ __launch_bounds__(1024) void deform_fused_kernel(
    const short* __restrict__ ht,   const short* __restrict__ fdw,
    const short* __restrict__ ppk,  const float* __restrict__ pwb,
    const short* __restrict__ wp,   const float* __restrict__ bias,
    const float* __restrict__ resid, float* __restrict__ outf,
    short* __restrict__ outb)
{
    int b = blockIdx.x >> 6;
    int row = blockIdx.x & 63;
    __shared__ int   i00[576], i01[576], i10[576], i11[576];
    __shared__ float c00[576], c01[576], c10[576], c11[576];
    __shared__ float off_lds[NOFF_ * 64];
    __shared__ __align__(16) short sbuf[2][16384];   // 2 x 32KB (8 slabs)
    int t = threadIdx.x;
    int wv = t >> 6, lane = t & 63;
    int pq = lane >> 4, pr = lane & 15;

    // ---- stage A: pw offsets via MFMA (waves 0..7) ----
    if (wv < 8) {
        int ot = wv & 1, ptw = wv >> 1;
        int px = ptw * 16 + pr;
        const short8* fb8 = (const short8*)(fdw +
            ((size_t)b * HW_ + row * 64 + px) * C_);
        const short8* ap = (const short8*)ppk;
        floatx4 pacc = (floatx4){0.f, 0.f, 0.f, 0.f};
        #pragma unroll
        for (int sl = 0; sl < 8; ++sl) {
            short8 af = ap[(sl * 2 + ot) * 64 + lane];
            short8 bf = fb8[sl * 4 + pq];
            pacc = __builtin_amdgcn_mfma_f32_16x16x32_bf16(af, bf, pacc, 0, 0, 0);
        }
        #pragma unroll
        for (int r = 0; r < 4; ++r) {
            int o = ot * 16 + pq * 4 + r;
            if (o < NOFF_) off_lds[o * 64 + px] = pacc[r] + pwb[o];
        }
    }
    __syncthreads();

    // ---- stage B: bilinear coefficient tables ----
    if (t < 576) {
        int e = t;
        int k = e >> 6, p = e & 63;
        float offy = off_lds[(2 * k) * 64 + p];
        float offx = off_lds[(2 * k + 1) * 64 + p];
        float py = (float)row + (float)(k / 3 - 1) + offy;
        float px = (float)p   + (float)(k % 3 - 1) + offx;
        float y0f = floorf(py), x0f = floorf(px);
        float wy1 = py - y0f, wx1 = px - x0f;
        float wy0 = 1.f - wy1, wx0 = 1.f - wx1;
        float y1f = y0f + 1.f, x1f = x0f + 1.f;
        bool vy0 = (y0f >= 0.f) && (y0f <= 63.f);
        bool vy1 = (y1f >= 0.f) && (y1f <= 63.f);
        bool vx0 = (x0f >= 0.f) && (x0f <= 63.f);
        bool vx1 = (x1f >= 0.f) && (x1f <= 63.f);
        int iy0 = (int)fminf(fmaxf(y0f, 0.f), 63.f);
        int iy1 = (int)fminf(fmaxf(y1f, 0.f), 63.f);
        int ix0 = (int)fminf(fmaxf(x0f, 0.f), 63.f);
        int ix1 = (int)fminf(fmaxf(x1f, 0.f), 63.f);
        i00[e] = iy0 * 64 + ix0; i01[e] = iy0 * 64 + ix1;
        i10[e] = iy1 * 64 + ix0; i11[e] = iy1 * 64 + ix1;
        c00[e] = (vy0 && vx0) ? wy0 * wx0 : 0.f;
        c01[e] = (vy0 && vx1) ? wy0 * wx1 : 0.f;
        c10[e] = (vy1 && vx0) ? wy1 * wx0 : 0.f;
        c11[e] = (vy1 && vx1) ? wy1 * wx1 : 0.f;
    }
    __syncthreads();

    // ---- stage C: 9 taps x 8 slabs, double-buffered, prefetched ----
    int scb = t & 3, spx = (t >> 2) & 63, ssl0 = t >> 8;
    int u2 = spx * 4 + (scb ^ ((spx + (spx >> 2)) & 3));
    const short* hb = ht + ((size_t)b * HW_) * C_;
    const short* hb0 = hb + ssl0 * 32 + scb * 8;
    const short* hb1 = hb + (ssl0 + 4) * 32 + scb * 8;

    short8 ra[4], rb[4];
    auto prefetch = [&](int g) {
        int e = g * 64 + spx;
        int a00 = i00[e], a01 = i01[e], a10 = i10[e], a11 = i11[e];
        ra[0] = *(const short8*)(hb0 + (size_t)a00 * C_);
        ra[1] = *(const short8*)(hb0 + (size_t)a01 * C_);
        ra[2] = *(const short8*)(hb0 + (size_t)a10 * C_);
        ra[3] = *(const short8*)(hb0 + (size_t)a11 * C_);
        rb[0] = *(const short8*)(hb1 + (size_t)a00 * C_);
        rb[1] = *(const short8*)(hb1 + (size_t)a01 * C_);
        rb[2] = *(const short8*)(hb1 + (size_t)a10 * C_);
        rb[3] = *(const short8*)(hb1 + (size_t)a11 * C_);
    };
    auto stage_write = [&](int g, int bi) {
        int e = g * 64 + spx;
        float w00 = c00[e], w01 = c01[e], w10 = c10[e], w11 = c11[e];
        short8 va, vb;
        #pragma unroll
        for (int j = 0; j < 8; ++j) {
            va[j] = f2bf(w00 * bf2f(ra[0][j]) + w01 * bf2f(ra[1][j])
                       + w10 * bf2f(ra[2][j]) + w11 * bf2f(ra[3][j]));
            vb[j] = f2bf(w00 * bf2f(rb[0][j]) + w01 * bf2f(rb[1][j])
                       + w10 * bf2f(rb[2][j]) + w11 * bf2f(rb[3][j]));
        }
        *(short8*)&sbuf[bi][ssl0 * 2048 + u2 * 8] = va;
        *(short8*)&sbuf[bi][(ssl0 + 4) * 2048 + u2 * 8] = vb;
    };

    floatx4 acc[4];
    #pragma unroll
    for (int pt = 0; pt < 4; ++pt) acc[pt] = (floatx4){0.f, 0.f, 0.f, 0.f};
    int ub[4];
    #pragma unroll
    for (int pt = 0; pt < 4; ++pt) {
        int px2 = pt * 16 + pr;
        ub[pt] = px2 * 4 + (pq ^ ((px2 + (px2 >> 2)) & 3));
    }

    prefetch(0);
    stage_write(0, 0);
    prefetch(1);
    __syncthreads();

    const short8* wp8 = (const short8*)wp;
    for (int g = 0; g < 9; ++g) {
        const short* sb = sbuf[g & 1];
        #pragma unroll
        for (int half = 0; half < 2; ++half) {
            short8 af[4];
            #pragma unroll
            for (int q = 0; q < 4; ++q)
                af[q] = wp8[(size_t)((g * 8 + half * 4 + q) * 16 + wv) * 64 + lane];
            #pragma unroll
            for (int q = 0; q < 4; ++q) {
                int sl = half * 4 + q;
                #pragma unroll
                for (int pt = 0; pt < 4; ++pt) {
                    short8 bfv = *(const short8*)&sb[sl * 2048 + ub[pt] * 8];
                    acc[pt] = __builtin_amdgcn_mfma_f32_16x16x32_bf16(
                        af[q], bfv, acc[pt], 0, 0, 0);
                }
            }
        }
        if (g + 1 < 9) {
            stage_write(g + 1, (g + 1) & 1);
            if (g + 2 < 9) prefetch(g + 2);
        }
        __syncthreads();
    }

    // ---- epilogue ----
    #pragma unroll
    for (int r = 0; r < 4; ++r) {
        int o = wv * 16 + pq * 4 + r;
        float bo = bias[o];
        size_t obase = ((size_t)(b * C_ + o)) * HW_ + row * 64 + pr;
        #pragma unroll
        for (int pt = 0; pt < 4; ++pt) {
            float v = acc[pt][r] + bo;
            if (outf) {
                if (resid) v += resid[obase + pt * 16];
                outf[obase + pt * 16] = v;
            } else {
                outb[obase + pt * 16] = f2bf(v);
            }
        }
    }
}

// ---------------------------------------------------------------------------
extern "C" void kernel_launch(void* const* d_in, const int* in_sizes, int n_in,
                              void* d_out, int out_size, void* d_ws, size_t ws_size,
                              hipStream_t stream)
{
    const float* x     = (const float*)d_in[0];
    const float* gn1_g = (const float*)d_in[1];
    const float* gn1_b = (const float*)d_in[2];
    const float* dw1   = (const float*)d_in[3];
    const float* pw1   = (const float*)d_in[4];
    const float* pwb1  = (const float*)d_in[5];
    const float* w1    = (const float*)d_in[6];
    const float* b1    = (const float*)d_in[7];
    const float* gn2_g = (const float*)d_in[8];
    const float* gn2_b = (const float*)d_in[9];
    const float* dw2   = (const float*)d_in[10];
    const float* pw2   = (const float*)d_in[11];
    const float* pwb2  = (const float*)d_in[12];
    const float* w2    = (const float*)d_in[13];
    const float* b2    = (const float*)d_in[14];
    float* out = (float*)d_out;

    float* ws   = (float*)d_ws;
    short* y1b  = (short*)ws;                  // bf16 [B][C][HW]  (8 MB)
    short* hbf  = (short*)(ws + 2097152);      // bf16 [B][C][HW]  (8 MB)
    short* hbt  = (short*)(ws + 4194304);      // bf16 [B][HW][C]  (8 MB)
    short* fdwc = (short*)(ws + 6291456);      // bf16 [B][C][HW]  (8 MB)
    short* fdwt = (short*)(ws + 8388608);      // bf16 [B][HW][C]  (8 MB)
    short* wp1  = (short*)(ws + 10485760);     // 589,824 bf16
    short* wp2  = (short*)(ws + 10780672);     // 589,824 bf16
    short* ppk1 = (short*)(ws + 11075584);     // 8,192 bf16
    short* ppk2 = (short*)(ws + 11079680);     // 8,192 bf16

    wpack_all_kernel<<<4672, 256, 0, stream>>>(w1, w2, pw1, pw2,
                                               wp1, wp2, ppk1, ppk2);

    // layer 1
    gn_relu_f32_kernel<<<B_ * NG_, 1024, 0, stream>>>(x, gn1_g, gn1_b, hbf);
    dw7_kernel<<<B_ * C_, 256, 0, stream>>>(hbf, dw1, fdwc);
    transpose2_kernel<<<512, 256, 0, stream>>>(hbf, hbt, fdwc, fdwt);
    deform_fused_kernel<<<B_ * H_, 1024, 0, stream>>>(
        hbt, fdwt, ppk1, pwb1, wp1, b1, nullptr, nullptr, y1b);

    // layer 2 (+ residual x)
    gn_relu_bf16_kernel<<<B_ * NG_, 1024, 0, stream>>>(y1b, gn2_g, gn2_b, hbf);
    dw7_kernel<<<B_ * C_, 256, 0, stream>>>(hbf, dw2, fdwc);
    transpose2_kernel<<<512, 256, 0, stream>>>(hbf, hbt, fdwc, fdwt);
    deform_fused_kernel<<<B_ * H_, 1024, 0, stream>>>(
        hbt, fdwt, ppk2, pwb2, wp2, b2, x, out, nullptr);
}